// Round 5
// baseline (1095.455 us; speedup 1.0000x reference)
//
#include <hip/hip_runtime.h>
#include <hip/hip_fp16.h>
#include <math.h>

#define FDIM 32
#define NBASIS 8
#define WIN 16          // consecutive sorted edges per half-wave (register-run window)

constexpr float RCUT_C = 20.0f;
constexpr float PI_F = 3.14159265358979323846f;
constexpr float EV2KJ_C = 96.4853f;
constexpr float NM2A_C = 10.0f;

__device__ __forceinline__ float sigmoidf_(float z) { return 1.0f / (1.0f + __expf(-z)); }

// ---------------- CSR build: histogram, scan, scatter ----------------
__global__ __launch_bounds__(256) void hist_dst(
    const int* __restrict__ eidx, int* __restrict__ counts, int E)
{
    for (int e = blockIdx.x * 256 + threadIdx.x; e < E; e += gridDim.x * 256)
        atomicAdd(&counts[eidx[E + e]], 1);
}

__global__ __launch_bounds__(1024) void scan_counts(
    const int* __restrict__ counts, int* __restrict__ cursor, int N)
{
    __shared__ int lds[1024];
    const int t = threadIdx.x;
    const int chunk = (N + 1023) / 1024;
    const int start = t * chunk;
    const int end = min(start + chunk, N);
    int local = 0;
    for (int i = start; i < end; i++) local += counts[i];
    lds[t] = local;
    __syncthreads();
    for (int off = 1; off < 1024; off <<= 1) {
        int v = (t >= off) ? lds[t - off] : 0;
        __syncthreads();
        lds[t] += v;
        __syncthreads();
    }
    int run = lds[t] - local;
    for (int i = start; i < end; i++) {
        cursor[i] = run;
        run += counts[i];
    }
}

__global__ __launch_bounds__(256) void scatter_edges(
    const int* __restrict__ eidx, int* __restrict__ cursor,
    int2* __restrict__ order_sd, int E)
{
    for (int e = blockIdx.x * 256 + threadIdx.x; e < E; e += gridDim.x * 256) {
        int dst = eidx[E + e];
        int p = atomicAdd(&cursor[dst], 1);
        order_sd[p] = make_int2(eidx[e], dst);
    }
}

// ---------------- edge forward: barrier-free register-run merge ----------------
__global__ __launch_bounds__(256, 4) void edge_fwd_sorted(
    const float* __restrict__ pos, const int* __restrict__ types,
    const int2* __restrict__ order_sd,
    const float* __restrict__ Wr1, const float* __restrict__ br1,
    const float* __restrict__ Wr2, const float* __restrict__ temb,
    float* __restrict__ s_acc, float* __restrict__ v_acc, int E)
{
    const int lane = threadIdx.x & 31;
    const int g = threadIdx.x >> 5;
    const long long base_p = (long long)(blockIdx.x * 8 + g) * WIN;

    // weights -> VGPRs, once per half-wave
    float w1r[NBASIS];
    #pragma unroll
    for (int n = 0; n < NBASIS; n++) w1r[n] = Wr1[n * FDIM + lane];
    const float b1 = br1[lane];
    __half2 w2h[FDIM];   // (W2[f][lane], W2[f][lane+32]) as fp16 pair -> 32 VGPRs
    #pragma unroll
    for (int f = 0; f < FDIM; f++)
        w2h[f] = __floats2half2_rn(Wr2[f * 64 + lane], Wr2[f * 64 + 32 + lane]);
    const float te0 = temb[lane], te1 = temb[FDIM + lane], te2 = temb[2 * FDIM + lane];

    long long rem = (long long)E - base_p;
    int nIt = (rem < 0) ? 0 : ((rem < WIN) ? (int)rem : WIN);

    int runKey = -1;
    float sAcc = 0.f, vXA = 0.f, vYA = 0.f, vZA = 0.f;
    float pdx = 0.f, pdy = 0.f, pdz = 0.f;

    for (int i = 0; i < nIt; i++) {
        int2 sd = order_sd[base_p + i];
        if (sd.y != runKey) {
            if (runKey >= 0) {
                unsafeAtomicAdd(&s_acc[(size_t)runKey * 32 + lane], sAcc);
                unsafeAtomicAdd(&v_acc[(size_t)runKey * 96 + 0 * 32 + lane], vXA);
                unsafeAtomicAdd(&v_acc[(size_t)runKey * 96 + 1 * 32 + lane], vYA);
                unsafeAtomicAdd(&v_acc[(size_t)runKey * 96 + 2 * 32 + lane], vZA);
            }
            runKey = sd.y;
            sAcc = vXA = vYA = vZA = 0.f;
            pdx = pos[sd.y * 3 + 0] * NM2A_C;
            pdy = pos[sd.y * 3 + 1] * NM2A_C;
            pdz = pos[sd.y * 3 + 2] * NM2A_C;
        }
        float rx = pdx - pos[sd.x * 3 + 0] * NM2A_C;
        float ry = pdy - pos[sd.x * 3 + 1] * NM2A_C;
        float rz = pdz - pos[sd.x * 3 + 2] * NM2A_C;
        int tyi = types[sd.x];

        float r2 = rx * rx + ry * ry + rz * rz + 1e-12f;
        float r = sqrtf(r2);
        float rinv = 1.0f / r;
        float x = r * (1.0f / RCUT_C);
        float x2 = x * x, x4 = x2 * x2, x6 = x4 * x2, x7 = x6 * x, x8 = x6 * x2;
        float env = (x < 1.0f) ? (1.0f - 28.0f * x6 + 48.0f * x7 - 21.0f * x8) : 0.0f;

        float th = PI_F * x, s1, c1;
        __sincosf(th, &s1, &c1);
        float sp = 0.0f, sn = s1;
        float z = b1;
        #pragma unroll
        for (int n = 0; n < NBASIS; n++) {
            z += (sn * rinv) * w1r[n];
            float snx = 2.0f * c1 * sn - sp; sp = sn; sn = snx;
        }
        float sg = sigmoidf_(z);
        float q = z * sg;

        __half2 qp = __float2half2_rn(q);
        int qi = __builtin_bit_cast(int, qp);
        __half2 rwh = __float2half2_rn(0.0f);
        #pragma unroll
        for (int f = 0; f < FDIM; f++) {
            int t = __shfl(qi, f, 32);
            rwh = __hfma2(__builtin_bit_cast(__half2, t), w2h[f], rwh);
        }
        float rw0 = __low2float(rwh), rw1 = __high2float(rwh);

        float hs = (tyi == 0) ? te0 : ((tyi == 1) ? te1 : te2);
        sAcc += hs * rw0 * env;
        float hw1 = hs * rw1 * env;
        vXA += hw1 * rx * rinv;
        vYA += hw1 * ry * rinv;
        vZA += hw1 * rz * rinv;
    }
    if (runKey >= 0) {
        unsafeAtomicAdd(&s_acc[(size_t)runKey * 32 + lane], sAcc);
        unsafeAtomicAdd(&v_acc[(size_t)runKey * 96 + 0 * 32 + lane], vXA);
        unsafeAtomicAdd(&v_acc[(size_t)runKey * 96 + 1 * 32 + lane], vYA);
        unsafeAtomicAdd(&v_acc[(size_t)runKey * 96 + 2 * 32 + lane], vZA);
    }
}

// -------- atom MLP: energy partials + g_s/g_v (in-place over s/v) --------
__global__ __launch_bounds__(256) void atom_mlp(
    const int* __restrict__ types, const float* __restrict__ temb,
    const float* __restrict__ Wself, const float* __restrict__ Wo1,
    const float* __restrict__ bo1, const float* __restrict__ Wo2,
    float* __restrict__ s_acc, float* __restrict__ v_acc,
    float* __restrict__ e_partial, int N)
{
    __shared__ float sWs[FDIM * FDIM], sWsT[FDIM * FDIM];
    __shared__ float sWo1[2 * FDIM * FDIM], sWo1T[2 * FDIM * FDIM];
    __shared__ float sb[FDIM], sW2o[FDIM], sTE[96];
    __shared__ float gred[8];
    for (int i = threadIdx.x; i < FDIM * FDIM; i += 256) {
        sWs[i] = Wself[i];
        sWsT[i] = Wself[(i & 31) * FDIM + (i >> 5)];
    }
    for (int i = threadIdx.x; i < 2 * FDIM * FDIM; i += 256) {
        sWo1[i] = Wo1[i];
        sWo1T[i] = Wo1[(i & 63) * FDIM + (i >> 6)];
    }
    for (int i = threadIdx.x; i < FDIM; i += 256) { sb[i] = bo1[i]; sW2o[i] = Wo2[i]; }
    for (int i = threadIdx.x; i < 96; i += 256) sTE[i] = temb[i];
    __syncthreads();

    const int lane = threadIdx.x & 31;
    const int g = threadIdx.x >> 5;
    int a = blockIdx.x * 8 + g;
    const bool valid = (a < N);
    if (!valid) a = 0;

    float sv = s_acc[(size_t)a * FDIM + lane];
    float vx = v_acc[(size_t)a * 96 + 0 * 32 + lane];
    float vy = v_acc[(size_t)a * 96 + 1 * 32 + lane];
    float vz = v_acc[(size_t)a * 96 + 2 * 32 + lane];
    float h = sTE[types[a] * FDIM + lane];
    float vn = sqrtf(vx * vx + vy * vy + vz * vz + 1e-12f);

    float row = h;
    #pragma unroll
    for (int f = 0; f < FDIM; f++) {
        float t = __shfl(sv, f, 32);
        row += t * sWs[f * FDIM + lane];
    }
    float u = sb[lane];
    #pragma unroll
    for (int j = 0; j < FDIM; j++) {
        float rv = __shfl(row, j, 32);
        float vv = __shfl(vn, j, 32);
        u += rv * sWo1[j * FDIM + lane] + vv * sWo1[(j + FDIM) * FDIM + lane];
    }
    float sg = sigmoidf_(u);
    float au = u * sg;
    float pa = valid ? au * sW2o[lane] : 0.0f;
    #pragma unroll
    for (int m = 16; m; m >>= 1) pa += __shfl_xor(pa, m, 32);
    if (lane == 0) gred[g] = pa;

    float gu = sW2o[lane] * (sg * (1.0f + u * (1.0f - sg)));
    float gfr = 0.0f, gfv = 0.0f;
    #pragma unroll
    for (int k = 0; k < FDIM; k++) {
        float gv_ = __shfl(gu, k, 32);
        gfr += gv_ * sWo1T[k * 64 + lane];
        gfv += gv_ * sWo1T[k * 64 + 32 + lane];
    }
    float gs = 0.0f;
    #pragma unroll
    for (int k = 0; k < FDIM; k++) {
        float gr = __shfl(gfr, k, 32);
        gs += gr * sWsT[k * FDIM + lane];
    }
    __syncthreads();
    if (valid) {
        s_acc[(size_t)a * FDIM + lane] = gs;
        float sc = gfv / vn;
        v_acc[(size_t)a * 96 + 0 * 32 + lane] = sc * vx;
        v_acc[(size_t)a * 96 + 1 * 32 + lane] = sc * vy;
        v_acc[(size_t)a * 96 + 2 * 32 + lane] = sc * vz;
    }
    if (threadIdx.x == 0) {
        float t = 0.0f;
        #pragma unroll
        for (int i = 0; i < 8; i++) t += gred[i];
        e_partial[blockIdx.x] = t;
    }
}

// ---------------- edge backward: barrier-free register-run merge ----------------
__global__ __launch_bounds__(256, 4) void edge_bwd_sorted(
    const float* __restrict__ pos, const int* __restrict__ types,
    const int2* __restrict__ order_sd,
    const float* __restrict__ Wr1, const float* __restrict__ br1,
    const float* __restrict__ Wr2, const float* __restrict__ temb,
    const float* __restrict__ g_s, const float* __restrict__ g_v,
    float* __restrict__ forces, int E)
{
    const int lane = threadIdx.x & 31;
    const int g = threadIdx.x >> 5;
    const long long base_p = (long long)(blockIdx.x * 8 + g) * WIN;

    float w1r[NBASIS];
    #pragma unroll
    for (int n = 0; n < NBASIS; n++) w1r[n] = Wr1[n * FDIM + lane];
    const float b1 = br1[lane];
    __half2 w2h[FDIM];
    #pragma unroll
    for (int f = 0; f < FDIM; f++)
        w2h[f] = __floats2half2_rn(Wr2[f * 64 + lane], Wr2[f * 64 + 32 + lane]);
    const float te0 = temb[lane], te1 = temb[FDIM + lane], te2 = temb[2 * FDIM + lane];

    long long rem = (long long)E - base_p;
    int nIt = (rem < 0) ? 0 : ((rem < WIN) ? (int)rem : WIN);

    const float SC = EV2KJ_C * NM2A_C;
    int runKey = -1;
    float fAcc = 0.f;
    float pdx = 0.f, pdy = 0.f, pdz = 0.f;
    float gm0 = 0.f, gm1x = 0.f, gm1y = 0.f, gm1z = 0.f;

    for (int i = 0; i < nIt; i++) {
        int2 sd = order_sd[base_p + i];
        if (sd.y != runKey) {
            if (runKey >= 0 && lane < 3)
                unsafeAtomicAdd(&forces[(size_t)runKey * 3 + lane], -SC * fAcc);
            runKey = sd.y;
            fAcc = 0.f;
            pdx = pos[sd.y * 3 + 0] * NM2A_C;
            pdy = pos[sd.y * 3 + 1] * NM2A_C;
            pdz = pos[sd.y * 3 + 2] * NM2A_C;
            gm0  = g_s[(size_t)sd.y * FDIM + lane];
            gm1x = g_v[(size_t)sd.y * 96 + 0 * 32 + lane];
            gm1y = g_v[(size_t)sd.y * 96 + 1 * 32 + lane];
            gm1z = g_v[(size_t)sd.y * 96 + 2 * 32 + lane];
        }
        float rx = pdx - pos[sd.x * 3 + 0] * NM2A_C;
        float ry = pdy - pos[sd.x * 3 + 1] * NM2A_C;
        float rz = pdz - pos[sd.x * 3 + 2] * NM2A_C;
        int tyi = types[sd.x];

        float r2 = rx * rx + ry * ry + rz * rz + 1e-12f;
        float r = sqrtf(r2);
        float rinv = 1.0f / r;
        float x = r * (1.0f / RCUT_C);
        float x2 = x * x, x4 = x2 * x2, x5 = x4 * x, x6 = x4 * x2, x7 = x6 * x, x8 = x6 * x2;
        float env = (x < 1.0f) ? (1.0f - 28.0f * x6 + 48.0f * x7 - 21.0f * x8) : 0.0f;
        float denv = (x < 1.0f) ? (-168.0f * x5 + 336.0f * x6 - 168.0f * x7) * (1.0f / RCUT_C) : 0.0f;

        float th = PI_F * x, s1, c1;
        __sincosf(th, &s1, &c1);
        float sp = 0.0f, sn = s1, cp = 1.0f, cn = c1;
        float z = b1;
        float tacc = 0.0f;
        #pragma unroll
        for (int n = 0; n < NBASIS; n++) {
            float basis = sn * rinv;
            z += basis * w1r[n];
            float dbdr = (PI_F * (float)(n + 1) * (1.0f / RCUT_C)) * cn * rinv - basis * rinv;
            tacc += dbdr * w1r[n];
            float snx = 2.0f * c1 * sn - sp; sp = sn; sn = snx;
            float cnx = 2.0f * c1 * cn - cp; cp = cn; cn = cnx;
        }
        float sg = sigmoidf_(z);
        float q = z * sg;
        float tf = (sg * (1.0f + z * (1.0f - sg))) * tacc;

        int qi = __builtin_bit_cast(int, __float2half2_rn(q));
        int ti = __builtin_bit_cast(int, __float2half2_rn(tf));
        __half2 rwh = __float2half2_rn(0.0f);
        __half2 uuh = __float2half2_rn(0.0f);
        #pragma unroll
        for (int f = 0; f < FDIM; f++) {
            int tq = __shfl(qi, f, 32);
            int tt = __shfl(ti, f, 32);
            rwh = __hfma2(__builtin_bit_cast(__half2, tq), w2h[f], rwh);
            uuh = __hfma2(__builtin_bit_cast(__half2, tt), w2h[f], uuh);
        }
        float rw0 = __low2float(rwh), rw1 = __high2float(rwh);
        float u0 = __low2float(uuh), u1 = __high2float(uuh);

        float hs = (tyi == 0) ? te0 : ((tyi == 1) ? te1 : te2);
        float rhx = rx * rinv, rhy = ry * rinv, rhz = rz * rinv;
        float gw0 = hs * gm0;
        float gw1 = hs * (gm1x * rhx + gm1y * rhy + gm1z * rhz);
        float hw1 = hs * rw1 * env;
        float grx = hw1 * gm1x, gry = hw1 * gm1y, grz = hw1 * gm1z;
        float genv = gw0 * rw0 + gw1 * rw1;
        float pc = (gw0 * env) * u0 + (gw1 * env) * u1 + genv * denv;
        float pg = pc - (grx * rhx + gry * rhy + grz * rhz) * rinv;

        // channel-packed butterfly: lane%4 -> {Gx,Gy,Gz,beta}
        float a1 = grx + __shfl_xor(grx, 1, 32);
        float b1v = gry + __shfl_xor(gry, 1, 32);
        float c1v = grz + __shfl_xor(grz, 1, 32);
        float d1 = pg + __shfl_xor(pg, 1, 32);
        float e0 = (lane & 1) ? b1v : a1;
        float e1 = (lane & 1) ? d1 : c1v;
        e0 += __shfl_xor(e0, 2, 32);
        e1 += __shfl_xor(e1, 2, 32);
        float v = (lane & 2) ? e1 : e0;
        v += __shfl_xor(v, 4, 32);
        v += __shfl_xor(v, 8, 32);
        v += __shfl_xor(v, 16, 32);
        float beta = __shfl(v, lane | 3, 32);

        if (lane < 3) {
            float rh_l = (lane == 0) ? rhx : ((lane == 1) ? rhy : rhz);
            float comp = v * rinv + rh_l * beta;
            unsafeAtomicAdd(&forces[(size_t)sd.x * 3 + lane], SC * comp);
            fAcc += comp;
        }
    }
    if (runKey >= 0 && lane < 3)
        unsafeAtomicAdd(&forces[(size_t)runKey * 3 + lane], -SC * fAcc);
}

// ---------------- reductions & correction ----------------
__global__ __launch_bounds__(256) void reduce_energy(
    const float* __restrict__ e_partial, int n, float* __restrict__ out)
{
    __shared__ float red[256];
    float s = 0.0f;
    for (int i = threadIdx.x; i < n; i += 256) s += e_partial[i];
    red[threadIdx.x] = s;
    __syncthreads();
    for (int k = 128; k; k >>= 1) {
        if (threadIdx.x < k) red[threadIdx.x] += red[threadIdx.x + k];
        __syncthreads();
    }
    if (threadIdx.x == 0) out[0] = red[0] * EV2KJ_C;
}

__global__ __launch_bounds__(256) void reduce_net(
    const float* __restrict__ f, const float* __restrict__ masses,
    float* __restrict__ accum, int N)
{
    float nx = 0, ny = 0, nz = 0, ms = 0;
    for (int i = blockIdx.x * 256 + threadIdx.x; i < N; i += gridDim.x * 256) {
        nx += f[i * 3 + 0]; ny += f[i * 3 + 1]; nz += f[i * 3 + 2]; ms += masses[i];
    }
    #pragma unroll
    for (int m = 32; m; m >>= 1) {
        nx += __shfl_xor(nx, m, 64);
        ny += __shfl_xor(ny, m, 64);
        nz += __shfl_xor(nz, m, 64);
        ms += __shfl_xor(ms, m, 64);
    }
    __shared__ float red[4][4];
    int w = threadIdx.x >> 6;
    if ((threadIdx.x & 63) == 0) { red[w][0] = nx; red[w][1] = ny; red[w][2] = nz; red[w][3] = ms; }
    __syncthreads();
    if (threadIdx.x == 0) {
        float a0 = 0, a1 = 0, a2 = 0, a3 = 0;
        for (int i = 0; i < 4; i++) { a0 += red[i][0]; a1 += red[i][1]; a2 += red[i][2]; a3 += red[i][3]; }
        unsafeAtomicAdd(accum + 0, a0);
        unsafeAtomicAdd(accum + 1, a1);
        unsafeAtomicAdd(accum + 2, a2);
        unsafeAtomicAdd(accum + 3, a3);
    }
}

__global__ __launch_bounds__(256) void correct_forces(
    float* __restrict__ f, const float* __restrict__ masses,
    const float* __restrict__ accum, int N)
{
    int i = blockIdx.x * 256 + threadIdx.x;
    if (i < N) {
        float c = masses[i] / accum[3];
        f[i * 3 + 0] -= c * accum[0];
        f[i * 3 + 1] -= c * accum[1];
        f[i * 3 + 2] -= c * accum[2];
    }
}

extern "C" void kernel_launch(void* const* d_in, const int* in_sizes, int n_in,
                              void* d_out, int out_size, void* d_ws, size_t ws_size,
                              hipStream_t stream)
{
    (void)n_in; (void)ws_size;
    const float* pos    = (const float*)d_in[0];
    const float* masses = (const float*)d_in[1];
    const float* temb   = (const float*)d_in[2];
    const float* Wr1    = (const float*)d_in[3];
    const float* br1    = (const float*)d_in[4];
    const float* Wr2    = (const float*)d_in[5];
    const float* Wself  = (const float*)d_in[6];
    const float* Wo1    = (const float*)d_in[7];
    const float* bo1    = (const float*)d_in[8];
    const float* Wo2    = (const float*)d_in[9];
    const int* types    = (const int*)d_in[10];
    const int* eidx     = (const int*)d_in[11];
    const int N = in_sizes[1];
    const int E = in_sizes[11] / 2;

    float* out = (float*)d_out;
    float* forces = out + 1;

    float* ws = (float*)d_ws;
    float* s_acc = ws;                               // N*32
    float* v_acc = s_acc + (size_t)N * FDIM;         // N*96
    int nAtomBlocks = (N + 7) / 8;
    float* e_partial = v_acc + (size_t)N * 96;       // nAtomBlocks
    float* accum = e_partial + nAtomBlocks;          // 4
    int* counts = (int*)(accum + 4);                 // N
    int* cursor = counts + N;                        // N
    int2* order_sd = (int2*)(cursor + N);            // E int2

    hipMemsetAsync(d_out, 0, (size_t)out_size * sizeof(float), stream);
    hipMemsetAsync(s_acc, 0, (size_t)N * 128 * sizeof(float), stream);
    hipMemsetAsync(counts, 0, (size_t)N * sizeof(int), stream);
    hipMemsetAsync(accum, 0, 4 * sizeof(float), stream);

    hist_dst<<<2048, 256, 0, stream>>>(eidx, counts, E);
    scan_counts<<<1, 1024, 0, stream>>>(counts, cursor, N);
    scatter_edges<<<2048, 256, 0, stream>>>(eidx, cursor, order_sd, E);

    int nHalf = (E + WIN - 1) / WIN;
    int nEdgeBlocks = (nHalf + 7) / 8;
    edge_fwd_sorted<<<nEdgeBlocks, 256, 0, stream>>>(pos, types, order_sd,
                                                     Wr1, br1, Wr2, temb,
                                                     s_acc, v_acc, E);
    atom_mlp<<<nAtomBlocks, 256, 0, stream>>>(types, temb, Wself, Wo1, bo1, Wo2,
                                              s_acc, v_acc, e_partial, N);
    reduce_energy<<<1, 256, 0, stream>>>(e_partial, nAtomBlocks, out);
    edge_bwd_sorted<<<nEdgeBlocks, 256, 0, stream>>>(pos, types, order_sd,
                                                     Wr1, br1, Wr2, temb,
                                                     s_acc, v_acc, forces, E);
    reduce_net<<<64, 256, 0, stream>>>(forces, masses, accum, N);
    correct_forces<<<(N + 255) / 256, 256, 0, stream>>>(forces, masses, accum, N);
}

// Round 6
// 980.220 us; speedup vs baseline: 1.1176x; 1.1176x over previous
//
#include <hip/hip_runtime.h>
#include <hip/hip_fp16.h>
#include <math.h>

#define FDIM 32
#define NBASIS 8
#define CHUNK 64          // edges per block
#define ITERS 8           // CHUNK / 8 half-waves

constexpr float RCUT_C = 20.0f;
constexpr float PI_F = 3.14159265358979323846f;
constexpr float EV2KJ_C = 96.4853f;
constexpr float NM2A_C = 10.0f;

__device__ __forceinline__ float sigmoidf_(float z) { return 1.0f / (1.0f + __expf(-z)); }

// ---------------- CSR build: histogram, scan, scatter ----------------
__global__ __launch_bounds__(256) void hist_dst(
    const int* __restrict__ eidx, int* __restrict__ counts, int E)
{
    for (int e = blockIdx.x * 256 + threadIdx.x; e < E; e += gridDim.x * 256)
        atomicAdd(&counts[eidx[E + e]], 1);
}

__global__ __launch_bounds__(1024) void scan_counts(
    const int* __restrict__ counts, int* __restrict__ cursor, int N)
{
    __shared__ int lds[1024];
    const int t = threadIdx.x;
    const int chunk = (N + 1023) / 1024;
    const int start = t * chunk;
    const int end = min(start + chunk, N);
    int local = 0;
    for (int i = start; i < end; i++) local += counts[i];
    lds[t] = local;
    __syncthreads();
    for (int off = 1; off < 1024; off <<= 1) {
        int v = (t >= off) ? lds[t - off] : 0;
        __syncthreads();
        lds[t] += v;
        __syncthreads();
    }
    int run = lds[t] - local;
    for (int i = start; i < end; i++) {
        cursor[i] = run;
        run += counts[i];
    }
}

__global__ __launch_bounds__(256) void scatter_edges(
    const int* __restrict__ eidx, int* __restrict__ cursor,
    int2* __restrict__ order_sd, int E)
{
    for (int e = blockIdx.x * 256 + threadIdx.x; e < E; e += gridDim.x * 256) {
        int dst = eidx[E + e];
        int p = atomicAdd(&cursor[dst], 1);
        order_sd[p] = make_int2(eidx[e], dst);
    }
}

// ---------------- edge forward (chunked, sorted, LDS fp16 weights) ----------------
__global__ __launch_bounds__(256) void edge_fwd_sorted(
    const float* __restrict__ pos, const int* __restrict__ types,
    const int2* __restrict__ order_sd,
    const float* __restrict__ Wr1, const float* __restrict__ br1,
    const float* __restrict__ Wr2, const float* __restrict__ temb,
    float* __restrict__ s_acc, float* __restrict__ v_acc, int E)
{
    __shared__ float mrg[2][8][128];
    __shared__ int mkeyA[2][8];
    __shared__ __half2 sW2h[FDIM * 32];   // [f*32+lane] = (W2[f][lane], W2[f][lane+32])

    const int lane = threadIdx.x & 31;
    const int g = threadIdx.x >> 5;
    const int tid = threadIdx.x;
    const int base = blockIdx.x * CHUNK;

    for (int i = tid; i < FDIM * 32; i += 256) {
        int f = i >> 5, l = i & 31;
        sW2h[i] = __floats2half2_rn(Wr2[f * 64 + l], Wr2[f * 64 + 32 + l]);
    }
    // small weights -> VGPRs
    float w1r[NBASIS];
    #pragma unroll
    for (int n = 0; n < NBASIS; n++) w1r[n] = Wr1[n * FDIM + lane];
    const float b1 = br1[lane];
    const float te0 = temb[lane], te1 = temb[FDIM + lane], te2 = temb[2 * FDIM + lane];
    __syncthreads();

    int runKey = -1;
    float runAcc = 0.0f;

    for (int it = 0; it < ITERS; it++) {
        const int p = base + it * 8 + g;
        const bool valid = (p < E);
        int2 sd = valid ? order_sd[p] : make_int2(0, 0);

        float rx = (pos[sd.y * 3 + 0] - pos[sd.x * 3 + 0]) * NM2A_C;
        float ry = (pos[sd.y * 3 + 1] - pos[sd.x * 3 + 1]) * NM2A_C;
        float rz = (pos[sd.y * 3 + 2] - pos[sd.x * 3 + 2]) * NM2A_C;
        int tyi = types[sd.x];
        float r2 = rx * rx + ry * ry + rz * rz + 1e-12f;
        float r = sqrtf(r2);
        float rinv = 1.0f / r;
        float x = r * (1.0f / RCUT_C);
        float x2 = x * x, x4 = x2 * x2, x6 = x4 * x2, x7 = x6 * x, x8 = x6 * x2;
        float env = (x < 1.0f) ? (1.0f - 28.0f * x6 + 48.0f * x7 - 21.0f * x8) : 0.0f;

        float th = PI_F * x, s1, c1;
        __sincosf(th, &s1, &c1);
        float sp = 0.0f, sn = s1;
        float z = b1;
        #pragma unroll
        for (int n = 0; n < NBASIS; n++) {
            z += (sn * rinv) * w1r[n];
            float snx = 2.0f * c1 * sn - sp; sp = sn; sn = snx;
        }
        float sg = sigmoidf_(z);
        float q = z * sg;

        int qi = __builtin_bit_cast(int, __float2half2_rn(q));
        __half2 rwh = __float2half2_rn(0.0f);
        #pragma unroll
        for (int f = 0; f < FDIM; f++) {
            int t = __shfl(qi, f, 32);
            rwh = __hfma2(__builtin_bit_cast(__half2, t), sW2h[f * 32 + lane], rwh);
        }
        float rw0 = __low2float(rwh), rw1 = __high2float(rwh);

        float hs = (tyi == 0) ? te0 : ((tyi == 1) ? te1 : te2);
        float s_sum = hs * rw0 * env;
        float hw1 = hs * rw1 * env;

        const int buf = it & 1;
        mrg[buf][g][lane]      = s_sum;
        mrg[buf][g][32 + lane] = hw1 * rx * rinv;
        mrg[buf][g][64 + lane] = hw1 * ry * rinv;
        mrg[buf][g][96 + lane] = hw1 * rz * rinv;
        if (lane == 0) mkeyA[buf][g] = valid ? sd.y : -1;
        __syncthreads();

        if (tid < 128) {
            #pragma unroll
            for (int row = 0; row < 8; row++) {
                int k = mkeyA[buf][row];
                float val = mrg[buf][row][tid];
                if (k != runKey) {
                    if (runKey >= 0) {
                        if (tid < 32) unsafeAtomicAdd(&s_acc[(size_t)runKey * 32 + tid], runAcc);
                        else          unsafeAtomicAdd(&v_acc[(size_t)runKey * 96 + (tid - 32)], runAcc);
                    }
                    runKey = k; runAcc = val;
                } else runAcc += val;
            }
        }
    }
    if (tid < 128 && runKey >= 0) {
        if (tid < 32) unsafeAtomicAdd(&s_acc[(size_t)runKey * 32 + tid], runAcc);
        else          unsafeAtomicAdd(&v_acc[(size_t)runKey * 96 + (tid - 32)], runAcc);
    }
}

// -------- atom MLP: energy partials + g_s/g_v (in-place over s/v) --------
__global__ __launch_bounds__(256) void atom_mlp(
    const int* __restrict__ types, const float* __restrict__ temb,
    const float* __restrict__ Wself, const float* __restrict__ Wo1,
    const float* __restrict__ bo1, const float* __restrict__ Wo2,
    float* __restrict__ s_acc, float* __restrict__ v_acc,
    float* __restrict__ e_partial, int N)
{
    __shared__ float sWs[FDIM * FDIM], sWsT[FDIM * FDIM];
    __shared__ float sWo1[2 * FDIM * FDIM], sWo1T[2 * FDIM * FDIM];
    __shared__ float sb[FDIM], sW2o[FDIM], sTE[96];
    __shared__ float gred[8];
    for (int i = threadIdx.x; i < FDIM * FDIM; i += 256) {
        sWs[i] = Wself[i];
        sWsT[i] = Wself[(i & 31) * FDIM + (i >> 5)];
    }
    for (int i = threadIdx.x; i < 2 * FDIM * FDIM; i += 256) {
        sWo1[i] = Wo1[i];
        sWo1T[i] = Wo1[(i & 63) * FDIM + (i >> 6)];
    }
    for (int i = threadIdx.x; i < FDIM; i += 256) { sb[i] = bo1[i]; sW2o[i] = Wo2[i]; }
    for (int i = threadIdx.x; i < 96; i += 256) sTE[i] = temb[i];
    __syncthreads();

    const int lane = threadIdx.x & 31;
    const int g = threadIdx.x >> 5;
    int a = blockIdx.x * 8 + g;
    const bool valid = (a < N);
    if (!valid) a = 0;

    float sv = s_acc[(size_t)a * FDIM + lane];
    float vx = v_acc[(size_t)a * 96 + 0 * 32 + lane];
    float vy = v_acc[(size_t)a * 96 + 1 * 32 + lane];
    float vz = v_acc[(size_t)a * 96 + 2 * 32 + lane];
    float h = sTE[types[a] * FDIM + lane];
    float vn = sqrtf(vx * vx + vy * vy + vz * vz + 1e-12f);

    float row = h;
    #pragma unroll
    for (int f = 0; f < FDIM; f++) {
        float t = __shfl(sv, f, 32);
        row += t * sWs[f * FDIM + lane];
    }
    float u = sb[lane];
    #pragma unroll
    for (int j = 0; j < FDIM; j++) {
        float rv = __shfl(row, j, 32);
        float vv = __shfl(vn, j, 32);
        u += rv * sWo1[j * FDIM + lane] + vv * sWo1[(j + FDIM) * FDIM + lane];
    }
    float sg = sigmoidf_(u);
    float au = u * sg;
    float pa = valid ? au * sW2o[lane] : 0.0f;
    #pragma unroll
    for (int m = 16; m; m >>= 1) pa += __shfl_xor(pa, m, 32);
    if (lane == 0) gred[g] = pa;

    float gu = sW2o[lane] * (sg * (1.0f + u * (1.0f - sg)));
    float gfr = 0.0f, gfv = 0.0f;
    #pragma unroll
    for (int k = 0; k < FDIM; k++) {
        float gv_ = __shfl(gu, k, 32);
        gfr += gv_ * sWo1T[k * 64 + lane];
        gfv += gv_ * sWo1T[k * 64 + 32 + lane];
    }
    float gs = 0.0f;
    #pragma unroll
    for (int k = 0; k < FDIM; k++) {
        float gr = __shfl(gfr, k, 32);
        gs += gr * sWsT[k * FDIM + lane];
    }
    __syncthreads();
    if (valid) {
        s_acc[(size_t)a * FDIM + lane] = gs;
        float sc = gfv / vn;
        v_acc[(size_t)a * 96 + 0 * 32 + lane] = sc * vx;
        v_acc[(size_t)a * 96 + 1 * 32 + lane] = sc * vy;
        v_acc[(size_t)a * 96 + 2 * 32 + lane] = sc * vz;
    }
    if (threadIdx.x == 0) {
        float t = 0.0f;
        #pragma unroll
        for (int i = 0; i < 8; i++) t += gred[i];
        e_partial[blockIdx.x] = t;
    }
}

// ---------------- edge backward (chunked, u-trick, LDS fp16 weights) ----------------
__global__ __launch_bounds__(256) void edge_bwd_sorted(
    const float* __restrict__ pos, const int* __restrict__ types,
    const int2* __restrict__ order_sd,
    const float* __restrict__ Wr1, const float* __restrict__ br1,
    const float* __restrict__ Wr2, const float* __restrict__ temb,
    const float* __restrict__ g_s, const float* __restrict__ g_v,
    float* __restrict__ forces, int E)
{
    __shared__ float mrgF[2][8][4];
    __shared__ int mkeyA[2][8];
    __shared__ __half2 sW2h[FDIM * 32];

    const int lane = threadIdx.x & 31;
    const int g = threadIdx.x >> 5;
    const int tid = threadIdx.x;
    const int base = blockIdx.x * CHUNK;

    for (int i = tid; i < FDIM * 32; i += 256) {
        int f = i >> 5, l = i & 31;
        sW2h[i] = __floats2half2_rn(Wr2[f * 64 + l], Wr2[f * 64 + 32 + l]);
    }
    float w1r[NBASIS];
    #pragma unroll
    for (int n = 0; n < NBASIS; n++) w1r[n] = Wr1[n * FDIM + lane];
    const float b1 = br1[lane];
    const float te0 = temb[lane], te1 = temb[FDIM + lane], te2 = temb[2 * FDIM + lane];
    __syncthreads();

    const float SC = EV2KJ_C * NM2A_C;
    int runKey = -1;
    float runAcc = 0.0f;

    for (int it = 0; it < ITERS; it++) {
        const int p = base + it * 8 + g;
        const bool valid = (p < E);
        int2 sd = valid ? order_sd[p] : make_int2(0, 0);

        float rx = (pos[sd.y * 3 + 0] - pos[sd.x * 3 + 0]) * NM2A_C;
        float ry = (pos[sd.y * 3 + 1] - pos[sd.x * 3 + 1]) * NM2A_C;
        float rz = (pos[sd.y * 3 + 2] - pos[sd.x * 3 + 2]) * NM2A_C;
        int tyi = types[sd.x];
        float gm0  = g_s[(size_t)sd.y * FDIM + lane];
        float gm1x = g_v[(size_t)sd.y * 96 + 0 * 32 + lane];
        float gm1y = g_v[(size_t)sd.y * 96 + 1 * 32 + lane];
        float gm1z = g_v[(size_t)sd.y * 96 + 2 * 32 + lane];

        float r2 = rx * rx + ry * ry + rz * rz + 1e-12f;
        float r = sqrtf(r2);
        float rinv = 1.0f / r;
        float x = r * (1.0f / RCUT_C);
        float x2 = x * x, x4 = x2 * x2, x5 = x4 * x, x6 = x4 * x2, x7 = x6 * x, x8 = x6 * x2;
        float env = (x < 1.0f) ? (1.0f - 28.0f * x6 + 48.0f * x7 - 21.0f * x8) : 0.0f;
        float denv = (x < 1.0f) ? (-168.0f * x5 + 336.0f * x6 - 168.0f * x7) * (1.0f / RCUT_C) : 0.0f;

        float th = PI_F * x, s1, c1;
        __sincosf(th, &s1, &c1);
        float sp = 0.0f, sn = s1, cp = 1.0f, cn = c1;
        float z = b1;
        float tacc = 0.0f;
        #pragma unroll
        for (int n = 0; n < NBASIS; n++) {
            float basis = sn * rinv;
            z += basis * w1r[n];
            float dbdr = (PI_F * (float)(n + 1) * (1.0f / RCUT_C)) * cn * rinv - basis * rinv;
            tacc += dbdr * w1r[n];
            float snx = 2.0f * c1 * sn - sp; sp = sn; sn = snx;
            float cnx = 2.0f * c1 * cn - cp; cp = cn; cn = cnx;
        }
        float sg = sigmoidf_(z);
        float q = z * sg;
        float tf = (sg * (1.0f + z * (1.0f - sg))) * tacc;

        int qi = __builtin_bit_cast(int, __float2half2_rn(q));
        int ti = __builtin_bit_cast(int, __float2half2_rn(tf));
        __half2 rwh = __float2half2_rn(0.0f);
        __half2 uuh = __float2half2_rn(0.0f);
        #pragma unroll
        for (int f = 0; f < FDIM; f++) {
            int tq = __shfl(qi, f, 32);
            int tt = __shfl(ti, f, 32);
            __half2 w = sW2h[f * 32 + lane];
            rwh = __hfma2(__builtin_bit_cast(__half2, tq), w, rwh);
            uuh = __hfma2(__builtin_bit_cast(__half2, tt), w, uuh);
        }
        float rw0 = __low2float(rwh), rw1 = __high2float(rwh);
        float u0 = __low2float(uuh), u1 = __high2float(uuh);

        float hs = (tyi == 0) ? te0 : ((tyi == 1) ? te1 : te2);
        float rhx = rx * rinv, rhy = ry * rinv, rhz = rz * rinv;
        float gw0 = hs * gm0;
        float gw1 = hs * (gm1x * rhx + gm1y * rhy + gm1z * rhz);
        float hw1 = hs * rw1 * env;
        float grx = hw1 * gm1x, gry = hw1 * gm1y, grz = hw1 * gm1z;
        float genv = gw0 * rw0 + gw1 * rw1;
        float pc = (gw0 * env) * u0 + (gw1 * env) * u1 + genv * denv;
        float pg = pc - (grx * rhx + gry * rhy + grz * rhz) * rinv;

        // channel-packed butterfly: lane%4 -> {Gx,Gy,Gz,beta}
        float a1 = grx + __shfl_xor(grx, 1, 32);
        float b1v = gry + __shfl_xor(gry, 1, 32);
        float c1v = grz + __shfl_xor(grz, 1, 32);
        float d1 = pg + __shfl_xor(pg, 1, 32);
        float e0 = (lane & 1) ? b1v : a1;
        float e1 = (lane & 1) ? d1 : c1v;
        e0 += __shfl_xor(e0, 2, 32);
        e1 += __shfl_xor(e1, 2, 32);
        float v = (lane & 2) ? e1 : e0;
        v += __shfl_xor(v, 4, 32);
        v += __shfl_xor(v, 8, 32);
        v += __shfl_xor(v, 16, 32);
        float beta = __shfl(v, lane | 3, 32);

        const int buf = it & 1;
        if (lane < 3) {
            float rh_l = (lane == 0) ? rhx : ((lane == 1) ? rhy : rhz);
            float comp = v * rinv + rh_l * beta;
            if (valid) unsafeAtomicAdd(&forces[(size_t)sd.x * 3 + lane], SC * comp);
            mrgF[buf][g][lane] = comp;
        }
        if (lane == 0) mkeyA[buf][g] = valid ? sd.y : -1;
        __syncthreads();

        if (tid < 3) {
            #pragma unroll
            for (int row = 0; row < 8; row++) {
                int k = mkeyA[buf][row];
                float val = mrgF[buf][row][tid];
                if (k != runKey) {
                    if (runKey >= 0)
                        unsafeAtomicAdd(&forces[(size_t)runKey * 3 + tid], -SC * runAcc);
                    runKey = k; runAcc = val;
                } else runAcc += val;
            }
        }
    }
    if (tid < 3 && runKey >= 0)
        unsafeAtomicAdd(&forces[(size_t)runKey * 3 + tid], -SC * runAcc);
}

// ---------------- reductions & correction ----------------
__global__ __launch_bounds__(256) void reduce_energy(
    const float* __restrict__ e_partial, int n, float* __restrict__ out)
{
    __shared__ float red[256];
    float s = 0.0f;
    for (int i = threadIdx.x; i < n; i += 256) s += e_partial[i];
    red[threadIdx.x] = s;
    __syncthreads();
    for (int k = 128; k; k >>= 1) {
        if (threadIdx.x < k) red[threadIdx.x] += red[threadIdx.x + k];
        __syncthreads();
    }
    if (threadIdx.x == 0) out[0] = red[0] * EV2KJ_C;
}

__global__ __launch_bounds__(256) void reduce_net(
    const float* __restrict__ f, const float* __restrict__ masses,
    float* __restrict__ accum, int N)
{
    float nx = 0, ny = 0, nz = 0, ms = 0;
    for (int i = blockIdx.x * 256 + threadIdx.x; i < N; i += gridDim.x * 256) {
        nx += f[i * 3 + 0]; ny += f[i * 3 + 1]; nz += f[i * 3 + 2]; ms += masses[i];
    }
    #pragma unroll
    for (int m = 32; m; m >>= 1) {
        nx += __shfl_xor(nx, m, 64);
        ny += __shfl_xor(ny, m, 64);
        nz += __shfl_xor(nz, m, 64);
        ms += __shfl_xor(ms, m, 64);
    }
    __shared__ float red[4][4];
    int w = threadIdx.x >> 6;
    if ((threadIdx.x & 63) == 0) { red[w][0] = nx; red[w][1] = ny; red[w][2] = nz; red[w][3] = ms; }
    __syncthreads();
    if (threadIdx.x == 0) {
        float a0 = 0, a1 = 0, a2 = 0, a3 = 0;
        for (int i = 0; i < 4; i++) { a0 += red[i][0]; a1 += red[i][1]; a2 += red[i][2]; a3 += red[i][3]; }
        unsafeAtomicAdd(accum + 0, a0);
        unsafeAtomicAdd(accum + 1, a1);
        unsafeAtomicAdd(accum + 2, a2);
        unsafeAtomicAdd(accum + 3, a3);
    }
}

__global__ __launch_bounds__(256) void correct_forces(
    float* __restrict__ f, const float* __restrict__ masses,
    const float* __restrict__ accum, int N)
{
    int i = blockIdx.x * 256 + threadIdx.x;
    if (i < N) {
        float c = masses[i] / accum[3];
        f[i * 3 + 0] -= c * accum[0];
        f[i * 3 + 1] -= c * accum[1];
        f[i * 3 + 2] -= c * accum[2];
    }
}

extern "C" void kernel_launch(void* const* d_in, const int* in_sizes, int n_in,
                              void* d_out, int out_size, void* d_ws, size_t ws_size,
                              hipStream_t stream)
{
    (void)n_in; (void)ws_size;
    const float* pos    = (const float*)d_in[0];
    const float* masses = (const float*)d_in[1];
    const float* temb   = (const float*)d_in[2];
    const float* Wr1    = (const float*)d_in[3];
    const float* br1    = (const float*)d_in[4];
    const float* Wr2    = (const float*)d_in[5];
    const float* Wself  = (const float*)d_in[6];
    const float* Wo1    = (const float*)d_in[7];
    const float* bo1    = (const float*)d_in[8];
    const float* Wo2    = (const float*)d_in[9];
    const int* types    = (const int*)d_in[10];
    const int* eidx     = (const int*)d_in[11];
    const int N = in_sizes[1];
    const int E = in_sizes[11] / 2;

    float* out = (float*)d_out;
    float* forces = out + 1;

    float* ws = (float*)d_ws;
    float* s_acc = ws;                               // N*32
    float* v_acc = s_acc + (size_t)N * FDIM;         // N*96
    int nAtomBlocks = (N + 7) / 8;
    float* e_partial = v_acc + (size_t)N * 96;       // nAtomBlocks
    float* accum = e_partial + nAtomBlocks;          // 4
    int* counts = (int*)(accum + 4);                 // N
    int* cursor = counts + N;                        // N
    int2* order_sd = (int2*)(cursor + N);            // E int2

    hipMemsetAsync(d_out, 0, (size_t)out_size * sizeof(float), stream);
    hipMemsetAsync(s_acc, 0, (size_t)N * 128 * sizeof(float), stream);
    hipMemsetAsync(counts, 0, (size_t)N * sizeof(int), stream);
    hipMemsetAsync(accum, 0, 4 * sizeof(float), stream);

    hist_dst<<<2048, 256, 0, stream>>>(eidx, counts, E);
    scan_counts<<<1, 1024, 0, stream>>>(counts, cursor, N);
    scatter_edges<<<2048, 256, 0, stream>>>(eidx, cursor, order_sd, E);

    int nEdgeBlocks = (E + CHUNK - 1) / CHUNK;
    edge_fwd_sorted<<<nEdgeBlocks, 256, 0, stream>>>(pos, types, order_sd,
                                                     Wr1, br1, Wr2, temb,
                                                     s_acc, v_acc, E);
    atom_mlp<<<nAtomBlocks, 256, 0, stream>>>(types, temb, Wself, Wo1, bo1, Wo2,
                                              s_acc, v_acc, e_partial, N);
    reduce_energy<<<1, 256, 0, stream>>>(e_partial, nAtomBlocks, out);
    edge_bwd_sorted<<<nEdgeBlocks, 256, 0, stream>>>(pos, types, order_sd,
                                                     Wr1, br1, Wr2, temb,
                                                     s_acc, v_acc, forces, E);
    reduce_net<<<64, 256, 0, stream>>>(forces, masses, accum, N);
    correct_forces<<<(N + 255) / 256, 256, 0, stream>>>(forces, masses, accum, N);
}

// Round 7
// 718.741 us; speedup vs baseline: 1.5241x; 1.3638x over previous
//
#include <hip/hip_runtime.h>
#include <math.h>

#define FDIM 32
#define NBASIS 8
#define QP 40     // sQ row pad (f16 units), keeps 16B alignment (80B rows)
#define EP 20     // D-stage edge-dim pad (f16 units), 8B-aligned quads

constexpr float RCUT_C = 20.0f;
constexpr float PI_F = 3.14159265358979323846f;
constexpr float EV2KJ_C = 96.4853f;
constexpr float NM2A_C = 10.0f;

typedef _Float16 f16x8 __attribute__((ext_vector_type(8)));
typedef _Float16 f16x4 __attribute__((ext_vector_type(4)));
typedef float f32x4 __attribute__((ext_vector_type(4)));

__device__ __forceinline__ float sigmoidf_(float z) { return 1.0f / (1.0f + __expf(-z)); }

// ---------------- CSR build: histogram, scan, scatter ----------------
__global__ __launch_bounds__(256) void hist_dst(
    const int* __restrict__ eidx, int* __restrict__ counts, int E)
{
    for (int e = blockIdx.x * 256 + threadIdx.x; e < E; e += gridDim.x * 256)
        atomicAdd(&counts[eidx[E + e]], 1);
}

__global__ __launch_bounds__(1024) void scan_counts(
    const int* __restrict__ counts, int* __restrict__ cursor, int N)
{
    __shared__ int lds[1024];
    const int t = threadIdx.x;
    const int chunk = (N + 1023) / 1024;
    const int start = t * chunk;
    const int end = min(start + chunk, N);
    int local = 0;
    for (int i = start; i < end; i++) local += counts[i];
    lds[t] = local;
    __syncthreads();
    for (int off = 1; off < 1024; off <<= 1) {
        int v = (t >= off) ? lds[t - off] : 0;
        __syncthreads();
        lds[t] += v;
        __syncthreads();
    }
    int run = lds[t] - local;
    for (int i = start; i < end; i++) {
        cursor[i] = run;
        run += counts[i];
    }
}

__global__ __launch_bounds__(256) void scatter_edges(
    const int* __restrict__ eidx, int* __restrict__ cursor,
    int2* __restrict__ order_sd, int E)
{
    for (int e = blockIdx.x * 256 + threadIdx.x; e < E; e += gridDim.x * 256) {
        int dst = eidx[E + e];
        int p = atomicAdd(&cursor[dst], 1);
        order_sd[p] = make_int2(eidx[e], dst);
    }
}

// ---------------- edge forward: MFMA matvec, wave-self-contained ----------------
__global__ __launch_bounds__(256) void edge_fwd_mfma(
    const float* __restrict__ pos, const int* __restrict__ types,
    const int2* __restrict__ order_sd,
    const float* __restrict__ Wr1, const float* __restrict__ br1,
    const float* __restrict__ Wr2, const float* __restrict__ temb,
    float* __restrict__ s_acc, float* __restrict__ v_acc, int E)
{
    __shared__ _Float16 sQ[4][16][QP];      // [wave][edge][feature]
    __shared__ _Float16 sD[4][64][EP];      // [wave][channel][edge]
    __shared__ float sSt[4][16][4];         // env, rhx, rhy, rhz

    const int lane = threadIdx.x & 63;
    const int l32 = threadIdx.x & 31;
    const int hw = (threadIdx.x >> 5) & 1;
    const int w = threadIdx.x >> 6;
    const int base = blockIdx.x * 64 + w * 16;

    // small weights (feature = l32)
    float w1r[NBASIS];
    #pragma unroll
    for (int n = 0; n < NBASIS; n++) w1r[n] = Wr1[n * FDIM + l32];
    const float b1 = br1[l32];
    const float te0 = temb[l32], te1 = temb[FDIM + l32], te2 = temb[2 * FDIM + l32];

    // B fragments: tile t covers channels [16t,16t+16); lane: n=16t+(lane&15), k=(lane>>4)*8+j
    f16x8 bf[4];
    {
        const int kb = (lane >> 4) * 8, nb = lane & 15;
        #pragma unroll
        for (int t = 0; t < 4; t++)
            #pragma unroll
            for (int j = 0; j < 8; j++)
                bf[t][j] = (_Float16)Wr2[(kb + j) * 64 + t * 16 + nb];
    }

    // ---- phase 1: geometry + radial MLP, stage q ----
    #pragma unroll
    for (int i = 0; i < 8; i++) {
        const int m = hw * 8 + i;
        const int p = base + m;
        int2 sd = (p < E) ? order_sd[p] : make_int2(0, 0);

        float rx = (pos[sd.y * 3 + 0] - pos[sd.x * 3 + 0]) * NM2A_C;
        float ry = (pos[sd.y * 3 + 1] - pos[sd.x * 3 + 1]) * NM2A_C;
        float rz = (pos[sd.y * 3 + 2] - pos[sd.x * 3 + 2]) * NM2A_C;
        float r2 = rx * rx + ry * ry + rz * rz + 1e-12f;
        float r = sqrtf(r2);
        float rinv = 1.0f / r;
        float x = r * (1.0f / RCUT_C);
        float x2 = x * x, x4 = x2 * x2, x6 = x4 * x2, x7 = x6 * x, x8 = x6 * x2;
        float env = (x < 1.0f) ? (1.0f - 28.0f * x6 + 48.0f * x7 - 21.0f * x8) : 0.0f;

        float th = PI_F * x, s1, c1;
        __sincosf(th, &s1, &c1);
        float sp = 0.0f, sn = s1;
        float z = b1;
        #pragma unroll
        for (int n = 0; n < NBASIS; n++) {
            z += (sn * rinv) * w1r[n];
            float snx = 2.0f * c1 * sn - sp; sp = sn; sn = snx;
        }
        float q = z * sigmoidf_(z);
        sQ[w][m][l32] = (_Float16)q;
        float st = (l32 == 0) ? env : ((l32 == 1) ? rx * rinv : ((l32 == 2) ? ry * rinv : rz * rinv));
        if (l32 < 4) sSt[w][m][l32] = st;
    }

    // ---- phase 2: MFMA (A: m=lane&15, k=(lane>>4)*8+j ; D: col=lane&15, row=(lane>>4)*4+reg) ----
    {
        f16x8 aq = *(const f16x8*)&sQ[w][lane & 15][(lane >> 4) * 8];
        const f32x4 z4 = {0.f, 0.f, 0.f, 0.f};
        const int cb = lane & 15, e0 = (lane >> 4) * 4;
        #pragma unroll
        for (int t = 0; t < 4; t++) {
            f32x4 d = __builtin_amdgcn_mfma_f32_16x16x32_f16(aq, bf[t], z4, 0, 0, 0);
            f16x4 dh;
            #pragma unroll
            for (int r = 0; r < 4; r++) dh[r] = (_Float16)d[r];
            *(f16x4*)&sD[w][t * 16 + cb][e0] = dh;
        }
    }

    // ---- phase 3: epilogue with per-half-wave register run-merge ----
    int runKey = -1;
    float sAcc = 0.f, vXA = 0.f, vYA = 0.f, vZA = 0.f;
    #pragma unroll
    for (int i = 0; i < 8; i++) {
        const int m = hw * 8 + i;
        const int p = base + m;
        if (p >= E) break;
        int2 sd = order_sd[p];
        if (sd.y != runKey) {
            if (runKey >= 0) {
                unsafeAtomicAdd(&s_acc[(size_t)runKey * 32 + l32], sAcc);
                unsafeAtomicAdd(&v_acc[(size_t)runKey * 96 + 0 * 32 + l32], vXA);
                unsafeAtomicAdd(&v_acc[(size_t)runKey * 96 + 1 * 32 + l32], vYA);
                unsafeAtomicAdd(&v_acc[(size_t)runKey * 96 + 2 * 32 + l32], vZA);
            }
            runKey = sd.y;
            sAcc = vXA = vYA = vZA = 0.f;
        }
        float env = sSt[w][m][0], rhx = sSt[w][m][1], rhy = sSt[w][m][2], rhz = sSt[w][m][3];
        float rw0 = (float)sD[w][l32][m];
        float rw1 = (float)sD[w][32 + l32][m];
        int tyi = types[sd.x];
        float hs = (tyi == 0) ? te0 : ((tyi == 1) ? te1 : te2);
        sAcc += hs * rw0 * env;
        float hw1 = hs * rw1 * env;
        vXA += hw1 * rhx; vYA += hw1 * rhy; vZA += hw1 * rhz;
    }
    if (runKey >= 0) {
        unsafeAtomicAdd(&s_acc[(size_t)runKey * 32 + l32], sAcc);
        unsafeAtomicAdd(&v_acc[(size_t)runKey * 96 + 0 * 32 + l32], vXA);
        unsafeAtomicAdd(&v_acc[(size_t)runKey * 96 + 1 * 32 + l32], vYA);
        unsafeAtomicAdd(&v_acc[(size_t)runKey * 96 + 2 * 32 + l32], vZA);
    }
}

// -------- atom MLP: energy partials + g_s/g_v (in-place over s/v) --------
__global__ __launch_bounds__(256) void atom_mlp(
    const int* __restrict__ types, const float* __restrict__ temb,
    const float* __restrict__ Wself, const float* __restrict__ Wo1,
    const float* __restrict__ bo1, const float* __restrict__ Wo2,
    float* __restrict__ s_acc, float* __restrict__ v_acc,
    float* __restrict__ e_partial, int N)
{
    __shared__ float sWs[FDIM * FDIM], sWsT[FDIM * FDIM];
    __shared__ float sWo1[2 * FDIM * FDIM], sWo1T[2 * FDIM * FDIM];
    __shared__ float sb[FDIM], sW2o[FDIM], sTE[96];
    __shared__ float gred[8];
    for (int i = threadIdx.x; i < FDIM * FDIM; i += 256) {
        sWs[i] = Wself[i];
        sWsT[i] = Wself[(i & 31) * FDIM + (i >> 5)];
    }
    for (int i = threadIdx.x; i < 2 * FDIM * FDIM; i += 256) {
        sWo1[i] = Wo1[i];
        sWo1T[i] = Wo1[(i & 63) * FDIM + (i >> 6)];
    }
    for (int i = threadIdx.x; i < FDIM; i += 256) { sb[i] = bo1[i]; sW2o[i] = Wo2[i]; }
    for (int i = threadIdx.x; i < 96; i += 256) sTE[i] = temb[i];
    __syncthreads();

    const int lane = threadIdx.x & 31;
    const int g = threadIdx.x >> 5;
    int a = blockIdx.x * 8 + g;
    const bool valid = (a < N);
    if (!valid) a = 0;

    float sv = s_acc[(size_t)a * FDIM + lane];
    float vx = v_acc[(size_t)a * 96 + 0 * 32 + lane];
    float vy = v_acc[(size_t)a * 96 + 1 * 32 + lane];
    float vz = v_acc[(size_t)a * 96 + 2 * 32 + lane];
    float h = sTE[types[a] * FDIM + lane];
    float vn = sqrtf(vx * vx + vy * vy + vz * vz + 1e-12f);

    float row = h;
    #pragma unroll
    for (int f = 0; f < FDIM; f++) {
        float t = __shfl(sv, f, 32);
        row += t * sWs[f * FDIM + lane];
    }
    float u = sb[lane];
    #pragma unroll
    for (int j = 0; j < FDIM; j++) {
        float rv = __shfl(row, j, 32);
        float vv = __shfl(vn, j, 32);
        u += rv * sWo1[j * FDIM + lane] + vv * sWo1[(j + FDIM) * FDIM + lane];
    }
    float sg = sigmoidf_(u);
    float au = u * sg;
    float pa = valid ? au * sW2o[lane] : 0.0f;
    #pragma unroll
    for (int m = 16; m; m >>= 1) pa += __shfl_xor(pa, m, 32);
    if (lane == 0) gred[g] = pa;

    float gu = sW2o[lane] * (sg * (1.0f + u * (1.0f - sg)));
    float gfr = 0.0f, gfv = 0.0f;
    #pragma unroll
    for (int k = 0; k < FDIM; k++) {
        float gv_ = __shfl(gu, k, 32);
        gfr += gv_ * sWo1T[k * 64 + lane];
        gfv += gv_ * sWo1T[k * 64 + 32 + lane];
    }
    float gs = 0.0f;
    #pragma unroll
    for (int k = 0; k < FDIM; k++) {
        float gr = __shfl(gfr, k, 32);
        gs += gr * sWsT[k * FDIM + lane];
    }
    __syncthreads();
    if (valid) {
        s_acc[(size_t)a * FDIM + lane] = gs;
        float sc = gfv / vn;
        v_acc[(size_t)a * 96 + 0 * 32 + lane] = sc * vx;
        v_acc[(size_t)a * 96 + 1 * 32 + lane] = sc * vy;
        v_acc[(size_t)a * 96 + 2 * 32 + lane] = sc * vz;
    }
    if (threadIdx.x == 0) {
        float t = 0.0f;
        #pragma unroll
        for (int i = 0; i < 8; i++) t += gred[i];
        e_partial[blockIdx.x] = t;
    }
}

// ---------------- edge backward: MFMA matvec (q & tf), wave-self-contained ----------------
__global__ __launch_bounds__(256) void edge_bwd_mfma(
    const float* __restrict__ pos, const int* __restrict__ types,
    const int2* __restrict__ order_sd,
    const float* __restrict__ Wr1, const float* __restrict__ br1,
    const float* __restrict__ Wr2, const float* __restrict__ temb,
    const float* __restrict__ g_s, const float* __restrict__ g_v,
    float* __restrict__ forces, int E)
{
    __shared__ _Float16 sQ[4][16][QP];
    __shared__ _Float16 sT[4][16][QP];
    __shared__ _Float16 sDq[4][64][EP];
    __shared__ _Float16 sDt[4][64][EP];
    __shared__ float sSt[4][16][8];   // rinv, env, denv, rhx, rhy, rhz

    const int lane = threadIdx.x & 63;
    const int l32 = threadIdx.x & 31;
    const int hw = (threadIdx.x >> 5) & 1;
    const int w = threadIdx.x >> 6;
    const int base = blockIdx.x * 64 + w * 16;

    float w1r[NBASIS];
    #pragma unroll
    for (int n = 0; n < NBASIS; n++) w1r[n] = Wr1[n * FDIM + l32];
    const float b1 = br1[l32];
    const float te0 = temb[l32], te1 = temb[FDIM + l32], te2 = temb[2 * FDIM + l32];

    f16x8 bf[4];
    {
        const int kb = (lane >> 4) * 8, nb = lane & 15;
        #pragma unroll
        for (int t = 0; t < 4; t++)
            #pragma unroll
            for (int j = 0; j < 8; j++)
                bf[t][j] = (_Float16)Wr2[(kb + j) * 64 + t * 16 + nb];
    }

    // ---- phase 1 ----
    #pragma unroll
    for (int i = 0; i < 8; i++) {
        const int m = hw * 8 + i;
        const int p = base + m;
        int2 sd = (p < E) ? order_sd[p] : make_int2(0, 0);

        float rx = (pos[sd.y * 3 + 0] - pos[sd.x * 3 + 0]) * NM2A_C;
        float ry = (pos[sd.y * 3 + 1] - pos[sd.x * 3 + 1]) * NM2A_C;
        float rz = (pos[sd.y * 3 + 2] - pos[sd.x * 3 + 2]) * NM2A_C;
        float r2 = rx * rx + ry * ry + rz * rz + 1e-12f;
        float r = sqrtf(r2);
        float rinv = 1.0f / r;
        float x = r * (1.0f / RCUT_C);
        float x2 = x * x, x4 = x2 * x2, x5 = x4 * x, x6 = x4 * x2, x7 = x6 * x, x8 = x6 * x2;
        float env = (x < 1.0f) ? (1.0f - 28.0f * x6 + 48.0f * x7 - 21.0f * x8) : 0.0f;
        float denv = (x < 1.0f) ? (-168.0f * x5 + 336.0f * x6 - 168.0f * x7) * (1.0f / RCUT_C) : 0.0f;

        float th = PI_F * x, s1, c1;
        __sincosf(th, &s1, &c1);
        float sp = 0.0f, sn = s1, cp = 1.0f, cn = c1;
        float z = b1;
        float tacc = 0.0f;
        #pragma unroll
        for (int n = 0; n < NBASIS; n++) {
            float basis = sn * rinv;
            z += basis * w1r[n];
            float dbdr = (PI_F * (float)(n + 1) * (1.0f / RCUT_C)) * cn * rinv - basis * rinv;
            tacc += dbdr * w1r[n];
            float snx = 2.0f * c1 * sn - sp; sp = sn; sn = snx;
            float cnx = 2.0f * c1 * cn - cp; cp = cn; cn = cnx;
        }
        float sg = sigmoidf_(z);
        float q = z * sg;
        float tf = (sg * (1.0f + z * (1.0f - sg))) * tacc;
        sQ[w][m][l32] = (_Float16)q;
        sT[w][m][l32] = (_Float16)tf;
        float st = (l32 == 0) ? rinv : ((l32 == 1) ? env : ((l32 == 2) ? denv :
                   ((l32 == 3) ? rx * rinv : ((l32 == 4) ? ry * rinv : rz * rinv))));
        if (l32 < 6) sSt[w][m][l32] = st;
    }

    // ---- phase 2: 8 MFMAs ----
    {
        f16x8 aq = *(const f16x8*)&sQ[w][lane & 15][(lane >> 4) * 8];
        f16x8 at = *(const f16x8*)&sT[w][lane & 15][(lane >> 4) * 8];
        const f32x4 z4 = {0.f, 0.f, 0.f, 0.f};
        const int cb = lane & 15, e0 = (lane >> 4) * 4;
        #pragma unroll
        for (int t = 0; t < 4; t++) {
            f32x4 dq = __builtin_amdgcn_mfma_f32_16x16x32_f16(aq, bf[t], z4, 0, 0, 0);
            f32x4 dt = __builtin_amdgcn_mfma_f32_16x16x32_f16(at, bf[t], z4, 0, 0, 0);
            f16x4 hq, ht;
            #pragma unroll
            for (int r = 0; r < 4; r++) { hq[r] = (_Float16)dq[r]; ht[r] = (_Float16)dt[r]; }
            *(f16x4*)&sDq[w][t * 16 + cb][e0] = hq;
            *(f16x4*)&sDt[w][t * 16 + cb][e0] = ht;
        }
    }

    // ---- phase 3: epilogue ----
    const float SC = EV2KJ_C * NM2A_C;
    int runKey = -1;
    float fAcc = 0.f;
    #pragma unroll
    for (int i = 0; i < 8; i++) {
        const int m = hw * 8 + i;
        const int p = base + m;
        if (p >= E) break;
        int2 sd = order_sd[p];
        if (sd.y != runKey) {
            if (runKey >= 0 && l32 < 3)
                unsafeAtomicAdd(&forces[(size_t)runKey * 3 + l32], -SC * fAcc);
            runKey = sd.y;
            fAcc = 0.f;
        }
        float rinv = sSt[w][m][0], env = sSt[w][m][1], denv = sSt[w][m][2];
        float rhx = sSt[w][m][3], rhy = sSt[w][m][4], rhz = sSt[w][m][5];
        float rw0 = (float)sDq[w][l32][m];
        float rw1 = (float)sDq[w][32 + l32][m];
        float u0  = (float)sDt[w][l32][m];
        float u1  = (float)sDt[w][32 + l32][m];

        float gm0  = g_s[(size_t)sd.y * FDIM + l32];
        float gm1x = g_v[(size_t)sd.y * 96 + 0 * 32 + l32];
        float gm1y = g_v[(size_t)sd.y * 96 + 1 * 32 + l32];
        float gm1z = g_v[(size_t)sd.y * 96 + 2 * 32 + l32];
        int tyi = types[sd.x];
        float hs = (tyi == 0) ? te0 : ((tyi == 1) ? te1 : te2);

        float gw0 = hs * gm0;
        float gw1 = hs * (gm1x * rhx + gm1y * rhy + gm1z * rhz);
        float hw1 = hs * rw1 * env;
        float grx = hw1 * gm1x, gry = hw1 * gm1y, grz = hw1 * gm1z;
        float genv = gw0 * rw0 + gw1 * rw1;
        float pc = (gw0 * env) * u0 + (gw1 * env) * u1 + genv * denv;
        float pg = pc - (grx * rhx + gry * rhy + grz * rhz) * rinv;

        // channel-packed butterfly: lane%4 -> {Gx,Gy,Gz,beta}
        float a1 = grx + __shfl_xor(grx, 1, 32);
        float b1v = gry + __shfl_xor(gry, 1, 32);
        float c1v = grz + __shfl_xor(grz, 1, 32);
        float d1 = pg + __shfl_xor(pg, 1, 32);
        float e0v = (l32 & 1) ? b1v : a1;
        float e1v = (l32 & 1) ? d1 : c1v;
        e0v += __shfl_xor(e0v, 2, 32);
        e1v += __shfl_xor(e1v, 2, 32);
        float v = (l32 & 2) ? e1v : e0v;
        v += __shfl_xor(v, 4, 32);
        v += __shfl_xor(v, 8, 32);
        v += __shfl_xor(v, 16, 32);
        float beta = __shfl(v, l32 | 3, 32);

        if (l32 < 3) {
            float rh_l = (l32 == 0) ? rhx : ((l32 == 1) ? rhy : rhz);
            float comp = v * rinv + rh_l * beta;
            unsafeAtomicAdd(&forces[(size_t)sd.x * 3 + l32], SC * comp);
            fAcc += comp;
        }
    }
    if (runKey >= 0 && l32 < 3)
        unsafeAtomicAdd(&forces[(size_t)runKey * 3 + l32], -SC * fAcc);
}

// ---------------- reductions & correction ----------------
__global__ __launch_bounds__(256) void reduce_energy(
    const float* __restrict__ e_partial, int n, float* __restrict__ out)
{
    __shared__ float red[256];
    float s = 0.0f;
    for (int i = threadIdx.x; i < n; i += 256) s += e_partial[i];
    red[threadIdx.x] = s;
    __syncthreads();
    for (int k = 128; k; k >>= 1) {
        if (threadIdx.x < k) red[threadIdx.x] += red[threadIdx.x + k];
        __syncthreads();
    }
    if (threadIdx.x == 0) out[0] = red[0] * EV2KJ_C;
}

__global__ __launch_bounds__(256) void reduce_net(
    const float* __restrict__ f, const float* __restrict__ masses,
    float* __restrict__ accum, int N)
{
    float nx = 0, ny = 0, nz = 0, ms = 0;
    for (int i = blockIdx.x * 256 + threadIdx.x; i < N; i += gridDim.x * 256) {
        nx += f[i * 3 + 0]; ny += f[i * 3 + 1]; nz += f[i * 3 + 2]; ms += masses[i];
    }
    #pragma unroll
    for (int m = 32; m; m >>= 1) {
        nx += __shfl_xor(nx, m, 64);
        ny += __shfl_xor(ny, m, 64);
        nz += __shfl_xor(nz, m, 64);
        ms += __shfl_xor(ms, m, 64);
    }
    __shared__ float red[4][4];
    int w = threadIdx.x >> 6;
    if ((threadIdx.x & 63) == 0) { red[w][0] = nx; red[w][1] = ny; red[w][2] = nz; red[w][3] = ms; }
    __syncthreads();
    if (threadIdx.x == 0) {
        float a0 = 0, a1 = 0, a2 = 0, a3 = 0;
        for (int i = 0; i < 4; i++) { a0 += red[i][0]; a1 += red[i][1]; a2 += red[i][2]; a3 += red[i][3]; }
        unsafeAtomicAdd(accum + 0, a0);
        unsafeAtomicAdd(accum + 1, a1);
        unsafeAtomicAdd(accum + 2, a2);
        unsafeAtomicAdd(accum + 3, a3);
    }
}

__global__ __launch_bounds__(256) void correct_forces(
    float* __restrict__ f, const float* __restrict__ masses,
    const float* __restrict__ accum, int N)
{
    int i = blockIdx.x * 256 + threadIdx.x;
    if (i < N) {
        float c = masses[i] / accum[3];
        f[i * 3 + 0] -= c * accum[0];
        f[i * 3 + 1] -= c * accum[1];
        f[i * 3 + 2] -= c * accum[2];
    }
}

extern "C" void kernel_launch(void* const* d_in, const int* in_sizes, int n_in,
                              void* d_out, int out_size, void* d_ws, size_t ws_size,
                              hipStream_t stream)
{
    (void)n_in; (void)ws_size;
    const float* pos    = (const float*)d_in[0];
    const float* masses = (const float*)d_in[1];
    const float* temb   = (const float*)d_in[2];
    const float* Wr1    = (const float*)d_in[3];
    const float* br1    = (const float*)d_in[4];
    const float* Wr2    = (const float*)d_in[5];
    const float* Wself  = (const float*)d_in[6];
    const float* Wo1    = (const float*)d_in[7];
    const float* bo1    = (const float*)d_in[8];
    const float* Wo2    = (const float*)d_in[9];
    const int* types    = (const int*)d_in[10];
    const int* eidx     = (const int*)d_in[11];
    const int N = in_sizes[1];
    const int E = in_sizes[11] / 2;

    float* out = (float*)d_out;
    float* forces = out + 1;

    float* ws = (float*)d_ws;
    float* s_acc = ws;                               // N*32
    float* v_acc = s_acc + (size_t)N * FDIM;         // N*96
    int nAtomBlocks = (N + 7) / 8;
    float* e_partial = v_acc + (size_t)N * 96;       // nAtomBlocks
    float* accum = e_partial + nAtomBlocks;          // 4
    int* counts = (int*)(accum + 4);                 // N
    int* cursor = counts + N;                        // N
    int2* order_sd = (int2*)(cursor + N);            // E int2

    hipMemsetAsync(d_out, 0, (size_t)out_size * sizeof(float), stream);
    hipMemsetAsync(s_acc, 0, (size_t)N * 128 * sizeof(float), stream);
    hipMemsetAsync(counts, 0, (size_t)N * sizeof(int), stream);
    hipMemsetAsync(accum, 0, 4 * sizeof(float), stream);

    hist_dst<<<2048, 256, 0, stream>>>(eidx, counts, E);
    scan_counts<<<1, 1024, 0, stream>>>(counts, cursor, N);
    scatter_edges<<<2048, 256, 0, stream>>>(eidx, cursor, order_sd, E);

    int nEdgeBlocks = (E + 63) / 64;
    edge_fwd_mfma<<<nEdgeBlocks, 256, 0, stream>>>(pos, types, order_sd,
                                                   Wr1, br1, Wr2, temb,
                                                   s_acc, v_acc, E);
    atom_mlp<<<nAtomBlocks, 256, 0, stream>>>(types, temb, Wself, Wo1, bo1, Wo2,
                                              s_acc, v_acc, e_partial, N);
    reduce_energy<<<1, 256, 0, stream>>>(e_partial, nAtomBlocks, out);
    edge_bwd_mfma<<<nEdgeBlocks, 256, 0, stream>>>(pos, types, order_sd,
                                                   Wr1, br1, Wr2, temb,
                                                   s_acc, v_acc, forces, E);
    reduce_net<<<64, 256, 0, stream>>>(forces, masses, accum, N);
    correct_forces<<<(N + 255) / 256, 256, 0, stream>>>(forces, masses, accum, N);
}

// Round 8
// 679.723 us; speedup vs baseline: 1.6116x; 1.0574x over previous
//
#include <hip/hip_runtime.h>
#include <math.h>

#define FDIM 32
#define NBASIS 8
#define QP 40     // A-stage row pad (f16 units) -> 80B rows, 16B-aligned quads
#define EP 20     // D-stage edge-dim pad (f16 units)

constexpr float RCUT_C = 20.0f;
constexpr float PI_F = 3.14159265358979323846f;
constexpr float EV2KJ_C = 96.4853f;
constexpr float NM2A_C = 10.0f;

typedef _Float16 f16x8 __attribute__((ext_vector_type(8)));
typedef _Float16 f16x4 __attribute__((ext_vector_type(4)));
typedef float f32x4 __attribute__((ext_vector_type(4)));

__device__ __forceinline__ float sigmoidf_(float z) { return 1.0f / (1.0f + __expf(-z)); }

// ---------------- CSR build: histogram, scan, scatter ----------------
__global__ __launch_bounds__(256) void hist_dst(
    const int* __restrict__ eidx, int* __restrict__ counts, int E)
{
    for (int e = blockIdx.x * 256 + threadIdx.x; e < E; e += gridDim.x * 256)
        atomicAdd(&counts[eidx[E + e]], 1);
}

__global__ __launch_bounds__(1024) void scan_counts(
    const int* __restrict__ counts, int* __restrict__ cursor, int N)
{
    __shared__ int lds[1024];
    const int t = threadIdx.x;
    const int chunk = (N + 1023) / 1024;
    const int start = t * chunk;
    const int end = min(start + chunk, N);
    int local = 0;
    for (int i = start; i < end; i++) local += counts[i];
    lds[t] = local;
    __syncthreads();
    for (int off = 1; off < 1024; off <<= 1) {
        int v = (t >= off) ? lds[t - off] : 0;
        __syncthreads();
        lds[t] += v;
        __syncthreads();
    }
    int run = lds[t] - local;
    for (int i = start; i < end; i++) {
        cursor[i] = run;
        run += counts[i];
    }
}

__global__ __launch_bounds__(256) void scatter_edges(
    const int* __restrict__ eidx, int* __restrict__ cursor,
    int2* __restrict__ order_sd, int E)
{
    for (int e = blockIdx.x * 256 + threadIdx.x; e < E; e += gridDim.x * 256) {
        int dst = eidx[E + e];
        int p = atomicAdd(&cursor[dst], 1);
        order_sd[p] = make_int2(eidx[e], dst);
    }
}

// ---------------- edge forward: dual-MFMA (basis layer + W2), lane-parallel geometry ----------------
__global__ __launch_bounds__(256) void edge_fwd_mfma(
    const float* __restrict__ pos, const int* __restrict__ types,
    const int2* __restrict__ order_sd,
    const float* __restrict__ Wr1, const float* __restrict__ br1,
    const float* __restrict__ Wr2, const float* __restrict__ temb,
    float* __restrict__ s_acc, float* __restrict__ v_acc, int E)
{
    __shared__ _Float16 sA[4][16][QP];      // [wave][edge][k]: basis(8) || 0(24)
    __shared__ _Float16 sQ[4][16][QP];      // q in A-layout for MFMA2
    __shared__ _Float16 sD[4][64][EP];      // [wave][channel][edge]
    __shared__ float sSt[4][16][4];         // env, rhx, rhy, rhz

    const int lane = threadIdx.x & 63;
    const int l32 = threadIdx.x & 31;
    const int hw = (threadIdx.x >> 5) & 1;
    const int w = threadIdx.x >> 6;
    const int base = blockIdx.x * 64 + w * 16;

    const float te0 = temb[l32], te1 = temb[FDIM + l32], te2 = temb[2 * FDIM + l32];

    const int kb = (lane >> 4) * 8, nb = lane & 15;
    // B1 (basis layer -> z): B[k][n] = (k<8) ? W1[k][tile*16+n] : 0
    f16x8 bz[2];
    #pragma unroll
    for (int t = 0; t < 2; t++)
        #pragma unroll
        for (int j = 0; j < 8; j++) {
            int k = kb + j;
            bz[t][j] = (k < 8) ? (_Float16)Wr1[k * FDIM + t * 16 + nb] : (_Float16)0.0f;
        }
    // B2 (W2): tile t covers channels [16t,16t+16)
    f16x8 bf[4];
    #pragma unroll
    for (int t = 0; t < 4; t++)
        #pragma unroll
        for (int j = 0; j < 8; j++)
            bf[t][j] = (_Float16)Wr2[(kb + j) * 64 + t * 16 + nb];

    // ---- phase 0: lane-parallel geometry + basis (lanes 0..15, edge = lane) ----
    if (lane < 16) {
        const int p = base + lane;
        int2 sd = (p < E) ? order_sd[p] : make_int2(0, 0);
        float rx = (pos[sd.y * 3 + 0] - pos[sd.x * 3 + 0]) * NM2A_C;
        float ry = (pos[sd.y * 3 + 1] - pos[sd.x * 3 + 1]) * NM2A_C;
        float rz = (pos[sd.y * 3 + 2] - pos[sd.x * 3 + 2]) * NM2A_C;
        float r2 = rx * rx + ry * ry + rz * rz + 1e-12f;
        float r = sqrtf(r2);
        float rinv = 1.0f / r;
        float x = r * (1.0f / RCUT_C);
        float x2 = x * x, x4 = x2 * x2, x6 = x4 * x2, x7 = x6 * x, x8 = x6 * x2;
        float env = (x < 1.0f) ? (1.0f - 28.0f * x6 + 48.0f * x7 - 21.0f * x8) : 0.0f;

        float th = PI_F * x, s1, c1;
        __sincosf(th, &s1, &c1);
        float sp = 0.0f, sn = s1;
        _Float16 av[8];
        #pragma unroll
        for (int n = 0; n < NBASIS; n++) {
            av[n] = (_Float16)(sn * rinv);
            float snx = 2.0f * c1 * sn - sp; sp = sn; sn = snx;
        }
        *(f16x8*)&sA[w][lane][0] = *(f16x8*)&av[0];
        *(float4*)&sA[w][lane][8]  = make_float4(0.f, 0.f, 0.f, 0.f);
        *(float4*)&sA[w][lane][16] = make_float4(0.f, 0.f, 0.f, 0.f);
        *(float4*)&sA[w][lane][24] = make_float4(0.f, 0.f, 0.f, 0.f);
        sSt[w][lane][0] = env;
        sSt[w][lane][1] = rx * rinv;
        sSt[w][lane][2] = ry * rinv;
        sSt[w][lane][3] = rz * rinv;
    }

    // ---- phase 1: MFMA basis layer -> z, then silu -> sQ (transposed store) ----
    {
        f16x8 a1 = *(const f16x8*)&sA[w][lane & 15][kb];
        const f32x4 z4 = {0.f, 0.f, 0.f, 0.f};
        f32x4 Dz0 = __builtin_amdgcn_mfma_f32_16x16x32_f16(a1, bz[0], z4, 0, 0, 0);
        f32x4 Dz1 = __builtin_amdgcn_mfma_f32_16x16x32_f16(a1, bz[1], z4, 0, 0, 0);
        const int f0 = lane & 15, e0 = (lane >> 4) * 4;
        const float bb0 = br1[f0], bb1 = br1[16 + f0];
        #pragma unroll
        for (int t = 0; t < 2; t++) {
            f32x4 Dz = t ? Dz1 : Dz0;
            float bb = t ? bb1 : bb0;
            #pragma unroll
            for (int r = 0; r < 4; r++) {
                float z = Dz[r] + bb;
                float q = z * sigmoidf_(z);
                sQ[w][e0 + r][t * 16 + f0] = (_Float16)q;
            }
        }
    }

    // ---- phase 2: MFMA W2 -> sD ----
    {
        f16x8 aq = *(const f16x8*)&sQ[w][lane & 15][kb];
        const f32x4 z4 = {0.f, 0.f, 0.f, 0.f};
        const int cb = lane & 15, e0 = (lane >> 4) * 4;
        #pragma unroll
        for (int t = 0; t < 4; t++) {
            f32x4 d = __builtin_amdgcn_mfma_f32_16x16x32_f16(aq, bf[t], z4, 0, 0, 0);
            f16x4 dh;
            #pragma unroll
            for (int r = 0; r < 4; r++) dh[r] = (_Float16)d[r];
            *(f16x4*)&sD[w][t * 16 + cb][e0] = dh;
        }
    }

    // ---- phase 3: epilogue with per-half-wave register run-merge ----
    int runKey = -1;
    float sAcc = 0.f, vXA = 0.f, vYA = 0.f, vZA = 0.f;
    #pragma unroll
    for (int i = 0; i < 8; i++) {
        const int m = hw * 8 + i;
        const int p = base + m;
        if (p >= E) break;
        int2 sd = order_sd[p];
        if (sd.y != runKey) {
            if (runKey >= 0) {
                unsafeAtomicAdd(&s_acc[(size_t)runKey * 32 + l32], sAcc);
                unsafeAtomicAdd(&v_acc[(size_t)runKey * 96 + 0 * 32 + l32], vXA);
                unsafeAtomicAdd(&v_acc[(size_t)runKey * 96 + 1 * 32 + l32], vYA);
                unsafeAtomicAdd(&v_acc[(size_t)runKey * 96 + 2 * 32 + l32], vZA);
            }
            runKey = sd.y;
            sAcc = vXA = vYA = vZA = 0.f;
        }
        float env = sSt[w][m][0], rhx = sSt[w][m][1], rhy = sSt[w][m][2], rhz = sSt[w][m][3];
        float rw0 = (float)sD[w][l32][m];
        float rw1 = (float)sD[w][32 + l32][m];
        int tyi = types[sd.x];
        float hs = (tyi == 0) ? te0 : ((tyi == 1) ? te1 : te2);
        sAcc += hs * rw0 * env;
        float hw1 = hs * rw1 * env;
        vXA += hw1 * rhx; vYA += hw1 * rhy; vZA += hw1 * rhz;
    }
    if (runKey >= 0) {
        unsafeAtomicAdd(&s_acc[(size_t)runKey * 32 + l32], sAcc);
        unsafeAtomicAdd(&v_acc[(size_t)runKey * 96 + 0 * 32 + l32], vXA);
        unsafeAtomicAdd(&v_acc[(size_t)runKey * 96 + 1 * 32 + l32], vYA);
        unsafeAtomicAdd(&v_acc[(size_t)runKey * 96 + 2 * 32 + l32], vZA);
    }
}

// -------- atom MLP: energy partials + g_s/g_v (in-place over s/v) --------
__global__ __launch_bounds__(256) void atom_mlp(
    const int* __restrict__ types, const float* __restrict__ temb,
    const float* __restrict__ Wself, const float* __restrict__ Wo1,
    const float* __restrict__ bo1, const float* __restrict__ Wo2,
    float* __restrict__ s_acc, float* __restrict__ v_acc,
    float* __restrict__ e_partial, int N)
{
    __shared__ float sWs[FDIM * FDIM], sWsT[FDIM * FDIM];
    __shared__ float sWo1[2 * FDIM * FDIM], sWo1T[2 * FDIM * FDIM];
    __shared__ float sb[FDIM], sW2o[FDIM], sTE[96];
    __shared__ float gred[8];
    for (int i = threadIdx.x; i < FDIM * FDIM; i += 256) {
        sWs[i] = Wself[i];
        sWsT[i] = Wself[(i & 31) * FDIM + (i >> 5)];
    }
    for (int i = threadIdx.x; i < 2 * FDIM * FDIM; i += 256) {
        sWo1[i] = Wo1[i];
        sWo1T[i] = Wo1[(i & 63) * FDIM + (i >> 6)];
    }
    for (int i = threadIdx.x; i < FDIM; i += 256) { sb[i] = bo1[i]; sW2o[i] = Wo2[i]; }
    for (int i = threadIdx.x; i < 96; i += 256) sTE[i] = temb[i];
    __syncthreads();

    const int lane = threadIdx.x & 31;
    const int g = threadIdx.x >> 5;
    int a = blockIdx.x * 8 + g;
    const bool valid = (a < N);
    if (!valid) a = 0;

    float sv = s_acc[(size_t)a * FDIM + lane];
    float vx = v_acc[(size_t)a * 96 + 0 * 32 + lane];
    float vy = v_acc[(size_t)a * 96 + 1 * 32 + lane];
    float vz = v_acc[(size_t)a * 96 + 2 * 32 + lane];
    float h = sTE[types[a] * FDIM + lane];
    float vn = sqrtf(vx * vx + vy * vy + vz * vz + 1e-12f);

    float row = h;
    #pragma unroll
    for (int f = 0; f < FDIM; f++) {
        float t = __shfl(sv, f, 32);
        row += t * sWs[f * FDIM + lane];
    }
    float u = sb[lane];
    #pragma unroll
    for (int j = 0; j < FDIM; j++) {
        float rv = __shfl(row, j, 32);
        float vv = __shfl(vn, j, 32);
        u += rv * sWo1[j * FDIM + lane] + vv * sWo1[(j + FDIM) * FDIM + lane];
    }
    float sg = sigmoidf_(u);
    float au = u * sg;
    float pa = valid ? au * sW2o[lane] : 0.0f;
    #pragma unroll
    for (int m = 16; m; m >>= 1) pa += __shfl_xor(pa, m, 32);
    if (lane == 0) gred[g] = pa;

    float gu = sW2o[lane] * (sg * (1.0f + u * (1.0f - sg)));
    float gfr = 0.0f, gfv = 0.0f;
    #pragma unroll
    for (int k = 0; k < FDIM; k++) {
        float gv_ = __shfl(gu, k, 32);
        gfr += gv_ * sWo1T[k * 64 + lane];
        gfv += gv_ * sWo1T[k * 64 + 32 + lane];
    }
    float gs = 0.0f;
    #pragma unroll
    for (int k = 0; k < FDIM; k++) {
        float gr = __shfl(gfr, k, 32);
        gs += gr * sWsT[k * FDIM + lane];
    }
    __syncthreads();
    if (valid) {
        s_acc[(size_t)a * FDIM + lane] = gs;
        float sc = gfv / vn;
        v_acc[(size_t)a * 96 + 0 * 32 + lane] = sc * vx;
        v_acc[(size_t)a * 96 + 1 * 32 + lane] = sc * vy;
        v_acc[(size_t)a * 96 + 2 * 32 + lane] = sc * vz;
    }
    if (threadIdx.x == 0) {
        float t = 0.0f;
        #pragma unroll
        for (int i = 0; i < 8; i++) t += gred[i];
        e_partial[blockIdx.x] = t;
    }
}

// ---------------- edge backward: dual-MFMA (z & tacc), lane-parallel geometry ----------------
__global__ __launch_bounds__(256) void edge_bwd_mfma(
    const float* __restrict__ pos, const int* __restrict__ types,
    const int2* __restrict__ order_sd,
    const float* __restrict__ Wr1, const float* __restrict__ br1,
    const float* __restrict__ Wr2, const float* __restrict__ temb,
    const float* __restrict__ g_s, const float* __restrict__ g_v,
    float* __restrict__ forces, int E)
{
    __shared__ _Float16 sA[4][16][QP];    // basis(8) || dbasis(8) || 0(16)
    __shared__ _Float16 sQ[4][16][QP];
    __shared__ _Float16 sT[4][16][QP];
    __shared__ _Float16 sDq[4][64][EP];
    __shared__ _Float16 sDt[4][64][EP];
    __shared__ float sSt[4][16][8];       // rinv, env, denv, rhx, rhy, rhz

    const int lane = threadIdx.x & 63;
    const int l32 = threadIdx.x & 31;
    const int hw = (threadIdx.x >> 5) & 1;
    const int w = threadIdx.x >> 6;
    const int base = blockIdx.x * 64 + w * 16;

    const float te0 = temb[l32], te1 = temb[FDIM + l32], te2 = temb[2 * FDIM + l32];

    const int kb = (lane >> 4) * 8, nb = lane & 15;
    // B1: z path (k<8 -> W1), tacc path (8<=k<16 -> W1)
    f16x8 bz[2], bt[2];
    #pragma unroll
    for (int t = 0; t < 2; t++)
        #pragma unroll
        for (int j = 0; j < 8; j++) {
            int k = kb + j;
            bz[t][j] = (k < 8) ? (_Float16)Wr1[k * FDIM + t * 16 + nb] : (_Float16)0.0f;
            bt[t][j] = (k >= 8 && k < 16) ? (_Float16)Wr1[(k - 8) * FDIM + t * 16 + nb] : (_Float16)0.0f;
        }
    f16x8 bf[4];
    #pragma unroll
    for (int t = 0; t < 4; t++)
        #pragma unroll
        for (int j = 0; j < 8; j++)
            bf[t][j] = (_Float16)Wr2[(kb + j) * 64 + t * 16 + nb];

    // ---- phase 0: lane-parallel geometry + basis/dbasis ----
    if (lane < 16) {
        const int p = base + lane;
        int2 sd = (p < E) ? order_sd[p] : make_int2(0, 0);
        float rx = (pos[sd.y * 3 + 0] - pos[sd.x * 3 + 0]) * NM2A_C;
        float ry = (pos[sd.y * 3 + 1] - pos[sd.x * 3 + 1]) * NM2A_C;
        float rz = (pos[sd.y * 3 + 2] - pos[sd.x * 3 + 2]) * NM2A_C;
        float r2 = rx * rx + ry * ry + rz * rz + 1e-12f;
        float r = sqrtf(r2);
        float rinv = 1.0f / r;
        float x = r * (1.0f / RCUT_C);
        float x2 = x * x, x4 = x2 * x2, x5 = x4 * x, x6 = x4 * x2, x7 = x6 * x, x8 = x6 * x2;
        float env = (x < 1.0f) ? (1.0f - 28.0f * x6 + 48.0f * x7 - 21.0f * x8) : 0.0f;
        float denv = (x < 1.0f) ? (-168.0f * x5 + 336.0f * x6 - 168.0f * x7) * (1.0f / RCUT_C) : 0.0f;

        float th = PI_F * x, s1, c1;
        __sincosf(th, &s1, &c1);
        float sp = 0.0f, sn = s1, cp = 1.0f, cn = c1;
        _Float16 av[16];
        #pragma unroll
        for (int n = 0; n < NBASIS; n++) {
            float basis = sn * rinv;
            float dbdr = (PI_F * (float)(n + 1) * (1.0f / RCUT_C)) * cn * rinv - basis * rinv;
            av[n] = (_Float16)basis;
            av[8 + n] = (_Float16)dbdr;
            float snx = 2.0f * c1 * sn - sp; sp = sn; sn = snx;
            float cnx = 2.0f * c1 * cn - cp; cp = cn; cn = cnx;
        }
        *(f16x8*)&sA[w][lane][0] = *(f16x8*)&av[0];
        *(f16x8*)&sA[w][lane][8] = *(f16x8*)&av[8];
        *(float4*)&sA[w][lane][16] = make_float4(0.f, 0.f, 0.f, 0.f);
        *(float4*)&sA[w][lane][24] = make_float4(0.f, 0.f, 0.f, 0.f);
        sSt[w][lane][0] = rinv;
        sSt[w][lane][1] = env;
        sSt[w][lane][2] = denv;
        sSt[w][lane][3] = rx * rinv;
        sSt[w][lane][4] = ry * rinv;
        sSt[w][lane][5] = rz * rinv;
    }

    // ---- phase 1: MFMA basis layer -> z, tacc; silu/tf -> sQ/sT ----
    {
        f16x8 a1 = *(const f16x8*)&sA[w][lane & 15][kb];
        const f32x4 z4 = {0.f, 0.f, 0.f, 0.f};
        f32x4 Dz0 = __builtin_amdgcn_mfma_f32_16x16x32_f16(a1, bz[0], z4, 0, 0, 0);
        f32x4 Dz1 = __builtin_amdgcn_mfma_f32_16x16x32_f16(a1, bz[1], z4, 0, 0, 0);
        f32x4 Dt0 = __builtin_amdgcn_mfma_f32_16x16x32_f16(a1, bt[0], z4, 0, 0, 0);
        f32x4 Dt1 = __builtin_amdgcn_mfma_f32_16x16x32_f16(a1, bt[1], z4, 0, 0, 0);
        const int f0 = lane & 15, e0 = (lane >> 4) * 4;
        const float bb0 = br1[f0], bb1 = br1[16 + f0];
        #pragma unroll
        for (int t = 0; t < 2; t++) {
            f32x4 Dz = t ? Dz1 : Dz0;
            f32x4 Dt = t ? Dt1 : Dt0;
            float bb = t ? bb1 : bb0;
            #pragma unroll
            for (int r = 0; r < 4; r++) {
                float z = Dz[r] + bb;
                float sg = sigmoidf_(z);
                float q = z * sg;
                float tf = (sg * (1.0f + z * (1.0f - sg))) * Dt[r];
                sQ[w][e0 + r][t * 16 + f0] = (_Float16)q;
                sT[w][e0 + r][t * 16 + f0] = (_Float16)tf;
            }
        }
    }

    // ---- phase 2: 8 MFMAs (W2 on q and tf) ----
    {
        f16x8 aq = *(const f16x8*)&sQ[w][lane & 15][kb];
        f16x8 at = *(const f16x8*)&sT[w][lane & 15][kb];
        const f32x4 z4 = {0.f, 0.f, 0.f, 0.f};
        const int cb = lane & 15, e0 = (lane >> 4) * 4;
        #pragma unroll
        for (int t = 0; t < 4; t++) {
            f32x4 dq = __builtin_amdgcn_mfma_f32_16x16x32_f16(aq, bf[t], z4, 0, 0, 0);
            f32x4 dt = __builtin_amdgcn_mfma_f32_16x16x32_f16(at, bf[t], z4, 0, 0, 0);
            f16x4 hq, ht;
            #pragma unroll
            for (int r = 0; r < 4; r++) { hq[r] = (_Float16)dq[r]; ht[r] = (_Float16)dt[r]; }
            *(f16x4*)&sDq[w][t * 16 + cb][e0] = hq;
            *(f16x4*)&sDt[w][t * 16 + cb][e0] = ht;
        }
    }

    // ---- phase 3: epilogue ----
    const float SC = EV2KJ_C * NM2A_C;
    int runKey = -1;
    float fAcc = 0.f;
    #pragma unroll
    for (int i = 0; i < 8; i++) {
        const int m = hw * 8 + i;
        const int p = base + m;
        if (p >= E) break;
        int2 sd = order_sd[p];
        if (sd.y != runKey) {
            if (runKey >= 0 && l32 < 3)
                unsafeAtomicAdd(&forces[(size_t)runKey * 3 + l32], -SC * fAcc);
            runKey = sd.y;
            fAcc = 0.f;
        }
        float rinv = sSt[w][m][0], env = sSt[w][m][1], denv = sSt[w][m][2];
        float rhx = sSt[w][m][3], rhy = sSt[w][m][4], rhz = sSt[w][m][5];
        float rw0 = (float)sDq[w][l32][m];
        float rw1 = (float)sDq[w][32 + l32][m];
        float u0  = (float)sDt[w][l32][m];
        float u1  = (float)sDt[w][32 + l32][m];

        float gm0  = g_s[(size_t)sd.y * FDIM + l32];
        float gm1x = g_v[(size_t)sd.y * 96 + 0 * 32 + l32];
        float gm1y = g_v[(size_t)sd.y * 96 + 1 * 32 + l32];
        float gm1z = g_v[(size_t)sd.y * 96 + 2 * 32 + l32];
        int tyi = types[sd.x];
        float hs = (tyi == 0) ? te0 : ((tyi == 1) ? te1 : te2);

        float gw0 = hs * gm0;
        float gw1 = hs * (gm1x * rhx + gm1y * rhy + gm1z * rhz);
        float hw1 = hs * rw1 * env;
        float grx = hw1 * gm1x, gry = hw1 * gm1y, grz = hw1 * gm1z;
        float genv = gw0 * rw0 + gw1 * rw1;
        float pc = (gw0 * env) * u0 + (gw1 * env) * u1 + genv * denv;
        float pg = pc - (grx * rhx + gry * rhy + grz * rhz) * rinv;

        // channel-packed butterfly: lane%4 -> {Gx,Gy,Gz,beta}
        float a1 = grx + __shfl_xor(grx, 1, 32);
        float b1v = gry + __shfl_xor(gry, 1, 32);
        float c1v = grz + __shfl_xor(grz, 1, 32);
        float d1 = pg + __shfl_xor(pg, 1, 32);
        float e0v = (l32 & 1) ? b1v : a1;
        float e1v = (l32 & 1) ? d1 : c1v;
        e0v += __shfl_xor(e0v, 2, 32);
        e1v += __shfl_xor(e1v, 2, 32);
        float v = (l32 & 2) ? e1v : e0v;
        v += __shfl_xor(v, 4, 32);
        v += __shfl_xor(v, 8, 32);
        v += __shfl_xor(v, 16, 32);
        float beta = __shfl(v, l32 | 3, 32);

        if (l32 < 3) {
            float rh_l = (l32 == 0) ? rhx : ((l32 == 1) ? rhy : rhz);
            float comp = v * rinv + rh_l * beta;
            unsafeAtomicAdd(&forces[(size_t)sd.x * 3 + l32], SC * comp);
            fAcc += comp;
        }
    }
    if (runKey >= 0 && l32 < 3)
        unsafeAtomicAdd(&forces[(size_t)runKey * 3 + l32], -SC * fAcc);
}

// ---------------- reductions & correction ----------------
__global__ __launch_bounds__(256) void reduce_energy(
    const float* __restrict__ e_partial, int n, float* __restrict__ out)
{
    __shared__ float red[256];
    float s = 0.0f;
    for (int i = threadIdx.x; i < n; i += 256) s += e_partial[i];
    red[threadIdx.x] = s;
    __syncthreads();
    for (int k = 128; k; k >>= 1) {
        if (threadIdx.x < k) red[threadIdx.x] += red[threadIdx.x + k];
        __syncthreads();
    }
    if (threadIdx.x == 0) out[0] = red[0] * EV2KJ_C;
}

__global__ __launch_bounds__(256) void reduce_net(
    const float* __restrict__ f, const float* __restrict__ masses,
    float* __restrict__ accum, int N)
{
    float nx = 0, ny = 0, nz = 0, ms = 0;
    for (int i = blockIdx.x * 256 + threadIdx.x; i < N; i += gridDim.x * 256) {
        nx += f[i * 3 + 0]; ny += f[i * 3 + 1]; nz += f[i * 3 + 2]; ms += masses[i];
    }
    #pragma unroll
    for (int m = 32; m; m >>= 1) {
        nx += __shfl_xor(nx, m, 64);
        ny += __shfl_xor(ny, m, 64);
        nz += __shfl_xor(nz, m, 64);
        ms += __shfl_xor(ms, m, 64);
    }
    __shared__ float red[4][4];
    int w = threadIdx.x >> 6;
    if ((threadIdx.x & 63) == 0) { red[w][0] = nx; red[w][1] = ny; red[w][2] = nz; red[w][3] = ms; }
    __syncthreads();
    if (threadIdx.x == 0) {
        float a0 = 0, a1 = 0, a2 = 0, a3 = 0;
        for (int i = 0; i < 4; i++) { a0 += red[i][0]; a1 += red[i][1]; a2 += red[i][2]; a3 += red[i][3]; }
        unsafeAtomicAdd(accum + 0, a0);
        unsafeAtomicAdd(accum + 1, a1);
        unsafeAtomicAdd(accum + 2, a2);
        unsafeAtomicAdd(accum + 3, a3);
    }
}

__global__ __launch_bounds__(256) void correct_forces(
    float* __restrict__ f, const float* __restrict__ masses,
    const float* __restrict__ accum, int N)
{
    int i = blockIdx.x * 256 + threadIdx.x;
    if (i < N) {
        float c = masses[i] / accum[3];
        f[i * 3 + 0] -= c * accum[0];
        f[i * 3 + 1] -= c * accum[1];
        f[i * 3 + 2] -= c * accum[2];
    }
}

extern "C" void kernel_launch(void* const* d_in, const int* in_sizes, int n_in,
                              void* d_out, int out_size, void* d_ws, size_t ws_size,
                              hipStream_t stream)
{
    (void)n_in; (void)ws_size;
    const float* pos    = (const float*)d_in[0];
    const float* masses = (const float*)d_in[1];
    const float* temb   = (const float*)d_in[2];
    const float* Wr1    = (const float*)d_in[3];
    const float* br1    = (const float*)d_in[4];
    const float* Wr2    = (const float*)d_in[5];
    const float* Wself  = (const float*)d_in[6];
    const float* Wo1    = (const float*)d_in[7];
    const float* bo1    = (const float*)d_in[8];
    const float* Wo2    = (const float*)d_in[9];
    const int* types    = (const int*)d_in[10];
    const int* eidx     = (const int*)d_in[11];
    const int N = in_sizes[1];
    const int E = in_sizes[11] / 2;

    float* out = (float*)d_out;
    float* forces = out + 1;

    float* ws = (float*)d_ws;
    float* s_acc = ws;                               // N*32
    float* v_acc = s_acc + (size_t)N * FDIM;         // N*96
    int nAtomBlocks = (N + 7) / 8;
    float* e_partial = v_acc + (size_t)N * 96;       // nAtomBlocks
    float* accum = e_partial + nAtomBlocks;          // 4
    int* counts = (int*)(accum + 4);                 // N
    int* cursor = counts + N;                        // N
    int2* order_sd = (int2*)(cursor + N);            // E int2

    hipMemsetAsync(d_out, 0, (size_t)out_size * sizeof(float), stream);
    hipMemsetAsync(s_acc, 0, (size_t)N * 128 * sizeof(float), stream);
    hipMemsetAsync(counts, 0, (size_t)N * sizeof(int), stream);
    hipMemsetAsync(accum, 0, 4 * sizeof(float), stream);

    hist_dst<<<2048, 256, 0, stream>>>(eidx, counts, E);
    scan_counts<<<1, 1024, 0, stream>>>(counts, cursor, N);
    scatter_edges<<<2048, 256, 0, stream>>>(eidx, cursor, order_sd, E);

    int nEdgeBlocks = (E + 63) / 64;
    edge_fwd_mfma<<<nEdgeBlocks, 256, 0, stream>>>(pos, types, order_sd,
                                                   Wr1, br1, Wr2, temb,
                                                   s_acc, v_acc, E);
    atom_mlp<<<nAtomBlocks, 256, 0, stream>>>(types, temb, Wself, Wo1, bo1, Wo2,
                                              s_acc, v_acc, e_partial, N);
    reduce_energy<<<1, 256, 0, stream>>>(e_partial, nAtomBlocks, out);
    edge_bwd_mfma<<<nEdgeBlocks, 256, 0, stream>>>(pos, types, order_sd,
                                                   Wr1, br1, Wr2, temb,
                                                   s_acc, v_acc, forces, E);
    reduce_net<<<64, 256, 0, stream>>>(forces, masses, accum, N);
    correct_forces<<<(N + 255) / 256, 256, 0, stream>>>(forces, masses, accum, N);
}